// Round 11
// baseline (411.505 us; speedup 1.0000x reference)
//
#include <hip/hip_runtime.h>
#include <math.h>

// ---- problem constants ----
constexpr int BB   = 1024;   // batch
constexpr int NN   = 2048;   // memory slots
constexpr int DD   = 64;     // memory width
constexpr int RR   = 4;      // read heads
constexpr float GAMMA = 0.95f;

// ---- d_out flat layout (float elements, reference return order) ----
constexpr size_t OUT_OUT = 0;                                   // (B, 768)
constexpr size_t OUT_MT  = OUT_OUT + (size_t)BB * 768;          // (B, N, D)
constexpr size_t OUT_RT  = OUT_MT  + (size_t)BB * NN * DD;      // (B, 256)
constexpr size_t OUT_HT  = OUT_RT  + (size_t)BB * 256;          // (B, 512)
constexpr size_t OUT_CT  = OUT_HT  + (size_t)BB * 512;          // (B, 512)
constexpr size_t OUT_WU  = OUT_CT  + (size_t)BB * 512;          // (B, N)
constexpr size_t OUT_WR  = OUT_WU  + (size_t)BB * NN;           // (B, R*N)

// ---- scratch inside M_t region, per-batch slice (header read before overwrite) ----
constexpr int SLICE   = NN * DD;       // 131072
constexpr int OFF_A   = 0;             // a: 256 floats
constexpr int OFF_G   = 8456 + NN;     // gates: 2048
constexpr int OFF_P   = OFF_G + 2048;  // p: 520
constexpr int OFF_K   = OFF_P + 520;   // k: 256

// ---- d_ws per-batch stash: 32 floats ----
constexpr int WS_STRIDE = 32;
constexpr int WS_SA  = 0;   // sigma(alpha): 4
constexpr int WS_KN  = 4;   // knorm: 4
constexpr int WS_IDX = 16;  // idx4 (int bits): 4

__device__ __forceinline__ float sigmoidf_(float x) { return 1.0f / (1.0f + __expf(-x)); }

typedef short short8 __attribute__((ext_vector_type(8)));
typedef float f32x4  __attribute__((ext_vector_type(4)));

// pack two f32 into one dword of 2 bf16 (round-to-nearest-even)
__device__ __forceinline__ unsigned bf16pack2(float a, float b) {
    unsigned ua = __float_as_uint(a), ub = __float_as_uint(b);
    ua = (ua + 0x7FFFu + ((ua >> 16) & 1u)) >> 16;
    ub = (ub + 0x7FFFu + ((ub >> 16) & 1u)) >> 16;
    return ua | (ub << 16);
}

// VALU-pipe cross-lane add within each 16-lane row: x + dpp(x).
template<int CTRL>
__device__ __forceinline__ float dpp_add(float x) {
    int y = __builtin_amdgcn_update_dpp(0, __float_as_int(x), CTRL, 0xF, 0xF, false);
    return x + __int_as_float(y);
}
template<int CTRL>
__device__ __forceinline__ void dpp_add5(float& a, float& b, float& c, float& d, float& e) {
    a = dpp_add<CTRL>(a); b = dpp_add<CTRL>(b); c = dpp_add<CTRL>(c);
    d = dpp_add<CTRL>(d); e = dpp_add<CTRL>(e);
}

// ===================== GEMM 1 (bf16 MFMA): gates = [x,r_prev,h_prev] @ [W_ih|W_hh]^T + b ==========
// 64x64 tile, 256 thr = 4 waves, each wave one 32x32 quadrant via 2x2 mfma_f32_16x16x32_bf16.
// LDS tiles 64 rows x 40 bf16 (pad 32->40 spreads banks). NT GEMM: A rows and W rows both
// k-contiguous -> identical fragment read pattern for A and B.
__global__ __launch_bounds__(256) void gemm_gates(
    const float* __restrict__ x, const float* __restrict__ rprev, const float* __restrict__ hprev,
    const float* __restrict__ Wih, const float* __restrict__ Whh,
    const float* __restrict__ bih, const float* __restrict__ bhh,
    float* __restrict__ out)
{
    __shared__ unsigned As[64][20];   // 64 x 40 bf16
    __shared__ unsigned Bs[64][20];
    const int t = threadIdx.x;
    const int wave = t >> 6, lane = t & 63;
    const int row0 = blockIdx.y * 64, col0 = blockIdx.x * 64;
    const int srow = t >> 2;          // staging row 0..63
    const int skq  = (t & 3) * 8;     // staging k offset: 0,8,16,24
    const int wm = wave >> 1, wn = wave & 1;
    const int lrow = lane & 15;
    const int ldw  = (lane >> 4) * 4; // dword offset of this lane's 8 bf16 in a 32-k row

    f32x4 acc00 = {0.f,0.f,0.f,0.f}, acc01 = {0.f,0.f,0.f,0.f};
    f32x4 acc10 = {0.f,0.f,0.f,0.f}, acc11 = {0.f,0.f,0.f,0.f};

    for (int k0 = 0; k0 < 1024; k0 += 32) {
        const int k = k0 + skq;
        // global loads (issued before the barrier -> overlap previous compute)
        float4 av0, av1, bv0, bv1;
        {
            const int ar = row0 + srow;
            if (k < 256)      { av0 = *(const float4*)(x + ar * 256 + k);
                                av1 = *(const float4*)(x + ar * 256 + k + 4); }
            else if (k < 512) { av0 = *(const float4*)(rprev + ar * 256 + (k - 256));
                                av1 = *(const float4*)(rprev + ar * 256 + (k - 256) + 4); }
            else              { av0 = *(const float4*)(hprev + ar * 512 + (k - 512));
                                av1 = *(const float4*)(hprev + ar * 512 + (k - 512) + 4); }
            const int br = col0 + srow;
            if (k < 512)      { bv0 = *(const float4*)(Wih + br * 512 + k);
                                bv1 = *(const float4*)(Wih + br * 512 + k + 4); }
            else              { bv0 = *(const float4*)(Whh + br * 512 + (k - 512));
                                bv1 = *(const float4*)(Whh + br * 512 + (k - 512) + 4); }
        }
        __syncthreads();   // previous iteration's fragment reads complete
        {
            unsigned* ap = &As[srow][skq >> 1];
            ap[0] = bf16pack2(av0.x, av0.y); ap[1] = bf16pack2(av0.z, av0.w);
            ap[2] = bf16pack2(av1.x, av1.y); ap[3] = bf16pack2(av1.z, av1.w);
            unsigned* bp = &Bs[srow][skq >> 1];
            bp[0] = bf16pack2(bv0.x, bv0.y); bp[1] = bf16pack2(bv0.z, bv0.w);
            bp[2] = bf16pack2(bv1.x, bv1.y); bp[3] = bf16pack2(bv1.z, bv1.w);
        }
        __syncthreads();   // tiles visible
        const short8 a0 = *(const short8*)&As[32 * wm + lrow][ldw];
        const short8 a1 = *(const short8*)&As[32 * wm + 16 + lrow][ldw];
        const short8 b0 = *(const short8*)&Bs[32 * wn + lrow][ldw];
        const short8 b1 = *(const short8*)&Bs[32 * wn + 16 + lrow][ldw];
        acc00 = __builtin_amdgcn_mfma_f32_16x16x32_bf16(a0, b0, acc00, 0, 0, 0);
        acc01 = __builtin_amdgcn_mfma_f32_16x16x32_bf16(a0, b1, acc01, 0, 0, 0);
        acc10 = __builtin_amdgcn_mfma_f32_16x16x32_bf16(a1, b0, acc10, 0, 0, 0);
        acc11 = __builtin_amdgcn_mfma_f32_16x16x32_bf16(a1, b1, acc11, 0, 0, 0);
    }

    // epilogue: C/D layout col = lane&15, row = (lane>>4)*4 + reg
    float* mt = out + OUT_MT;
    const int rbase = row0 + 32 * wm + (lane >> 4) * 4;
    #pragma unroll
    for (int ni = 0; ni < 2; ni++) {
        const int col = col0 + 32 * wn + 16 * ni + lrow;
        const float bb = bih[col] + bhh[col];
        #pragma unroll
        for (int reg = 0; reg < 4; reg++) {
            const float v0 = (ni == 0) ? acc00[reg] : acc01[reg];
            const float v1 = (ni == 0) ? acc10[reg] : acc11[reg];
            mt[(size_t)(rbase + reg) * SLICE + OFF_G + col] = v0 + bb;
            mt[(size_t)(rbase + 16 + reg) * SLICE + OFF_G + col] = v1 + bb;
        }
    }
}

// ===================== LSTM pointwise (float4) =====================
__global__ __launch_bounds__(256) void lstm_pw(const float* __restrict__ cprev, float* __restrict__ out)
{
    const size_t e0 = ((size_t)blockIdx.x * 256 + threadIdx.x) * 4;  // 0 .. B*512-4
    const int b = (int)(e0 >> 9), j = (int)(e0 & 511);
    const float* g = out + OUT_MT + (size_t)b * SLICE + OFF_G;
    const float4 ig = *(const float4*)(g + j);
    const float4 fg = *(const float4*)(g + 512 + j);
    const float4 gg = *(const float4*)(g + 1024 + j);
    const float4 og = *(const float4*)(g + 1536 + j);
    const float4 cp = *(const float4*)(cprev + e0);
    float4 c, h;
    c.x = sigmoidf_(fg.x) * cp.x + sigmoidf_(ig.x) * tanhf(gg.x);
    c.y = sigmoidf_(fg.y) * cp.y + sigmoidf_(ig.y) * tanhf(gg.y);
    c.z = sigmoidf_(fg.z) * cp.z + sigmoidf_(ig.z) * tanhf(gg.z);
    c.w = sigmoidf_(fg.w) * cp.w + sigmoidf_(ig.w) * tanhf(gg.w);
    h.x = sigmoidf_(og.x) * tanhf(c.x);
    h.y = sigmoidf_(og.y) * tanhf(c.y);
    h.z = sigmoidf_(og.z) * tanhf(c.z);
    h.w = sigmoidf_(og.w) * tanhf(c.w);
    *(float4*)(out + OUT_CT + e0) = c;
    *(float4*)(out + OUT_HT + e0) = h;
    *(float4*)(out + (size_t)b * 768 + j) = h;
}

// ===================== GEMM 2: p = h_t @ W_lin^T + b_lin  (1024 x 516, K=512) =====================
__global__ __launch_bounds__(256) void gemm_p(
    const float* __restrict__ Wlin, const float* __restrict__ blin, float* __restrict__ out)
{
    __shared__ float As[16][68];
    __shared__ float Bs[16][68];
    const int t = threadIdx.x;
    const int row0 = blockIdx.y * 64, col0 = blockIdx.x * 64;
    const int tx = t & 15, ty = t >> 4;
    const int li = t >> 2;
    const int kq = (t & 3) * 4;
    const float* ht = out + OUT_HT;
    float acc[4][4] = {};

    for (int k0 = 0; k0 < 512; k0 += 16) {
        const int k = k0 + kq;
        {
            const int row = row0 + li;
            const float4 av = *(const float4*)(ht + (size_t)row * 512 + k);
            As[kq + 0][li] = av.x; As[kq + 1][li] = av.y;
            As[kq + 2][li] = av.z; As[kq + 3][li] = av.w;
        }
        {
            const int j = col0 + li;
            float4 bv = make_float4(0.f, 0.f, 0.f, 0.f);
            if (j < 516) bv = *(const float4*)(Wlin + j * 512 + k);
            Bs[kq + 0][li] = bv.x; Bs[kq + 1][li] = bv.y;
            Bs[kq + 2][li] = bv.z; Bs[kq + 3][li] = bv.w;
        }
        __syncthreads();
        #pragma unroll
        for (int kk = 0; kk < 16; kk++) {
            const float4 a4 = *(const float4*)&As[kk][ty * 4];
            const float4 b4 = *(const float4*)&Bs[kk][tx * 4];
            acc[0][0] += a4.x * b4.x; acc[0][1] += a4.x * b4.y; acc[0][2] += a4.x * b4.z; acc[0][3] += a4.x * b4.w;
            acc[1][0] += a4.y * b4.x; acc[1][1] += a4.y * b4.y; acc[1][2] += a4.y * b4.z; acc[1][3] += a4.y * b4.w;
            acc[2][0] += a4.z * b4.x; acc[2][1] += a4.z * b4.y; acc[2][2] += a4.z * b4.z; acc[2][3] += a4.z * b4.w;
            acc[3][0] += a4.w * b4.x; acc[3][1] += a4.w * b4.y; acc[3][2] += a4.w * b4.z; acc[3][3] += a4.w * b4.w;
        }
        __syncthreads();
    }
    float* mt = out + OUT_MT;
    #pragma unroll
    for (int ci = 0; ci < 4; ci++) {
        int row = row0 + ty * 4 + ci;
        #pragma unroll
        for (int cj = 0; cj < 4; cj++) {
            int col = col0 + tx * 4 + cj;
            if (col < 516)
                mt[(size_t)row * SLICE + OFF_P + col] = acc[ci][cj] + blin[col];
        }
    }
}

// ===================== k/a/sigma_alpha/knorm + argmin4, fused ==========
__global__ __launch_bounds__(256) void kp_argmin_k(
    const float* __restrict__ wuprev, float* __restrict__ out, float* __restrict__ ws)
{
    const int b = blockIdx.x, t = threadIdx.x;
    float* mt = out + OUT_MT;
    const size_t sl = (size_t)b * SLICE;
    float* wsb = ws + (size_t)b * WS_STRIDE;

    // ---- part 1: k, a, sigma(alpha), ||k|| ----
    {
        const float* p = mt + sl + OFF_P;
        const int r = t >> 6, d = t & 63;
        float kv = tanhf(p[r * 64 + d]);
        float av = tanhf(p[256 + r * 64 + d]);
        mt[sl + OFF_K + r * 64 + d] = kv;
        mt[sl + OFF_A + r * 64 + d] = av;
        float s2 = kv * kv;
        #pragma unroll
        for (int off = 1; off < 64; off <<= 1) s2 += __shfl_xor(s2, off);
        if (d == 0) wsb[WS_KN + r] = sqrtf(s2);
        if (t < 4) wsb[WS_SA + t] = sigmoidf_(p[512 + t]);
    }

    // ---- part 2: 4 smallest wu_prev indices (tie -> larger index) ----
    __shared__ float sval[256];
    __shared__ int   sidx[256];
    __shared__ int   chosen[4];
    float wu8[8];
    #pragma unroll
    for (int i = 0; i < 8; i++) wu8[i] = wuprev[(size_t)b * NN + t + i * 256];

    for (int it = 0; it < 4; it++) {
        float bv = 3.4e38f; int bi = -1;
        #pragma unroll
        for (int i = 0; i < 8; i++) {
            int n = t + i * 256;
            bool skip = false;
            for (int j = 0; j < it; j++) skip = skip || (n == chosen[j]);
            float v = wu8[i];
            if (!skip && (v < bv || (v == bv && n > bi))) { bv = v; bi = n; }
        }
        sval[t] = bv; sidx[t] = bi;
        __syncthreads();
        for (int s = 128; s; s >>= 1) {
            if (t < s) {
                float v2 = sval[t + s]; int i2 = sidx[t + s];
                if (v2 < sval[t] || (v2 == sval[t] && i2 > sidx[t])) { sval[t] = v2; sidx[t] = i2; }
            }
            __syncthreads();
        }
        if (t == 0) chosen[it] = sidx[0];
        __syncthreads();
    }
    if (t < 4)
        ((int*)wsb)[WS_IDX + t] = chosen[t];
}

// ===================== FUSED memory pass + softmax finalize =====================
// One block per batch (512 thr = 8 waves). Single M_prev read, single M_t write.
// Software-pipelined m4 prefetch; Z recomputed in phase 2 from the LDS e-buffer.
__global__ __launch_bounds__(512) void fused_mem(
    const float* __restrict__ Mprev, const float* __restrict__ wrprev,
    const float* __restrict__ wuprev,
    float* __restrict__ out, const float* __restrict__ ws)
{
    const int b = blockIdx.x, t = threadIdx.x;
    const int wave = t >> 6, lane = t & 63;
    const int row4 = lane >> 4, d4 = lane & 15;
    float* mt = out + OUT_MT;
    const size_t sl = (size_t)b * SLICE;
    const float* wsb = ws + (size_t)b * WS_STRIDE;

    __shared__ float4 s_e4[NN];     // 32 KB: e[n][r]; reused as lr in final merge
    __shared__ float  lz[8][4];     // per-wave partial Z

    // ---- header loads (sa/rck/id4 are wave-uniform -> SGPRs) ----
    float4 k4[4], a4[4]; float sa[4], rck[4]; int id4[4];
    #pragma unroll
    for (int r = 0; r < 4; r++) {
        k4[r] = *(const float4*)(mt + sl + OFF_K + r * 64 + d4 * 4);
        a4[r] = *(const float4*)(mt + sl + OFF_A + r * 64 + d4 * 4);
        sa[r]  = wsb[WS_SA + r];
        rck[r] = 1.0f / wsb[WS_KN + r];
        id4[r] = ((const int*)wsb)[WS_IDX + r];
    }
    __syncthreads();   // header fully read before any M_t row is overwritten

    const float* wrp = wrprev + (size_t)b * (RR * NN);
    const int kill = id4[0];
    const size_t mbase = (size_t)b * NN * DD + (size_t)(d4 * 4);

    float4 racc[4];
    #pragma unroll
    for (int r = 0; r < 4; r++) racc[r] = make_float4(0.f, 0.f, 0.f, 0.f);

    // prologue: load first row
    float4 m4 = *(const float4*)(Mprev + mbase + (size_t)(wave * 4 + row4) * DD);

    for (int it = 0; it < 64; it++) {
        const int n = it * 32 + wave * 4 + row4;
        const int nn = (n + 32) & (NN - 1);            // wrapped prefetch index (last iter harmless)
        const float4 m4n = *(const float4*)(Mprev + mbase + (size_t)nn * DD);  // prefetch next
        const float w0 = wrp[0 * NN + n];
        const float w1 = wrp[1 * NN + n];
        const float w2 = wrp[2 * NN + n];
        const float w3 = wrp[3 * NN + n];

        float nrm = m4.x * m4.x + m4.y * m4.y + m4.z * m4.z + m4.w * m4.w;
        float ip0 = k4[0].x * m4.x + k4[0].y * m4.y + k4[0].z * m4.z + k4[0].w * m4.w;
        float ip1 = k4[1].x * m4.x + k4[1].y * m4.y + k4[1].z * m4.z + k4[1].w * m4.w;
        float ip2 = k4[2].x * m4.x + k4[2].y * m4.y + k4[2].z * m4.z + k4[2].w * m4.w;
        float ip3 = k4[3].x * m4.x + k4[3].y * m4.y + k4[3].z * m4.z + k4[3].w * m4.w;
        // 16-lane reduce+broadcast on the VALU pipe (no DS traffic)
        dpp_add5<0xB1>(nrm, ip0, ip1, ip2, ip3);   // quad_perm xor1
        dpp_add5<0x4E>(nrm, ip0, ip1, ip2, ip3);   // quad_perm xor2
        dpp_add5<0x124>(nrm, ip0, ip1, ip2, ip3);  // row_ror:4
        dpp_add5<0x128>(nrm, ip0, ip1, ip2, ip3);  // row_ror:8

        const float rsn = rsqrtf(fmaxf(nrm, 1e-30f));
        const float e0 = __expf(ip0 * rck[0] * rsn);
        const float e1 = __expf(ip1 * rck[1] * rsn);
        const float e2 = __expf(ip2 * rck[2] * rsn);
        const float e3 = __expf(ip3 * rck[3] * rsn);
        if (d4 == 0) s_e4[n] = make_float4(e0, e1, e2, e3);

        // M_t row:  ww = sa*wrp + (1-sa)*wlu  ==  fma(sa, wrp - wlu, wlu)
        const float wlu = (n == id4[0] || n == id4[1] || n == id4[2] || n == id4[3]) ? 1.0f : 0.0f;
        float4 mtv = m4;
        if (n == kill) { mtv.x = 0.f; mtv.y = 0.f; mtv.z = 0.f; mtv.w = 0.f; }
        const float ww0 = fmaf(sa[0], w0 - wlu, wlu);
        const float ww1 = fmaf(sa[1], w1 - wlu, wlu);
        const float ww2 = fmaf(sa[2], w2 - wlu, wlu);
        const float ww3 = fmaf(sa[3], w3 - wlu, wlu);
        mtv.x += ww0 * a4[0].x + ww1 * a4[1].x + ww2 * a4[2].x + ww3 * a4[3].x;
        mtv.y += ww0 * a4[0].y + ww1 * a4[1].y + ww2 * a4[2].y + ww3 * a4[3].y;
        mtv.z += ww0 * a4[0].z + ww1 * a4[1].z + ww2 * a4[2].z + ww3 * a4[3].z;
        mtv.w += ww0 * a4[0].w + ww1 * a4[1].w + ww2 * a4[2].w + ww3 * a4[3].w;
        *(float4*)(mt + sl + (size_t)n * DD + d4 * 4) = mtv;

        // raw-softmax accumulation of r_t numerator
        racc[0].x += e0 * mtv.x; racc[0].y += e0 * mtv.y; racc[0].z += e0 * mtv.z; racc[0].w += e0 * mtv.w;
        racc[1].x += e1 * mtv.x; racc[1].y += e1 * mtv.y; racc[1].z += e1 * mtv.z; racc[1].w += e1 * mtv.w;
        racc[2].x += e2 * mtv.x; racc[2].y += e2 * mtv.y; racc[2].z += e2 * mtv.z; racc[2].w += e2 * mtv.w;
        racc[3].x += e3 * mtv.x; racc[3].y += e3 * mtv.y; racc[3].z += e3 * mtv.z; racc[3].w += e3 * mtv.w;

        m4 = m4n;   // rotate pipeline
    }

    // merge racc across the 4 row-groups within the wave (lane bits 4,5)
    #pragma unroll
    for (int off = 16; off < 64; off <<= 1) {
        #pragma unroll
        for (int r = 0; r < 4; r++) {
            racc[r].x += __shfl_xor(racc[r].x, off);
            racc[r].y += __shfl_xor(racc[r].y, off);
            racc[r].z += __shfl_xor(racc[r].z, off);
            racc[r].w += __shfl_xor(racc[r].w, off);
        }
    }
    __syncthreads();   // s_e4 now visible block-wide

    // ---- Z from s_e4 (wave shuffle reduce + 8-wave LDS merge) ----
    float z0 = 0.f, z1 = 0.f, z2 = 0.f, z3 = 0.f;
    #pragma unroll
    for (int i = 0; i < 4; i++) {
        const float4 e4 = s_e4[i * 512 + t];
        z0 += e4.x; z1 += e4.y; z2 += e4.z; z3 += e4.w;
    }
    #pragma unroll
    for (int off = 1; off < 64; off <<= 1) {
        z0 += __shfl_xor(z0, off); z1 += __shfl_xor(z1, off);
        z2 += __shfl_xor(z2, off); z3 += __shfl_xor(z3, off);
    }
    if (lane == 0) { lz[wave][0] = z0; lz[wave][1] = z1; lz[wave][2] = z2; lz[wave][3] = z3; }
    __syncthreads();
    float zi[4];
    #pragma unroll
    for (int r = 0; r < 4; r++) {
        float Z = 0.f;
        #pragma unroll
        for (int w = 0; w < 8; w++) Z += lz[w][r];
        zi[r] = 1.0f / Z;
    }

    // ---- phase 2: wr_t and wu_t (streaming; e from LDS) ----
    {
        float* wro = out + OUT_WR + (size_t)b * (RR * NN);
        float* wuo = out + OUT_WU + (size_t)b * NN;
        #pragma unroll
        for (int i = 0; i < 4; i++) {
            const int n = i * 512 + t;
            const float4 e4 = s_e4[n];
            const float wl = (n == id4[0] || n == id4[1] || n == id4[2] || n == id4[3]) ? 1.0f : 0.0f;
            const float wv0 = e4.x * zi[0], wv1 = e4.y * zi[1], wv2 = e4.z * zi[2], wv3 = e4.w * zi[3];
            wro[0 * NN + n] = wv0; wro[1 * NN + n] = wv1;
            wro[2 * NN + n] = wv2; wro[3 * NN + n] = wv3;
            float acc = wv0 + wv1 + wv2 + wv3;
            acc += fmaf(sa[0], wrp[0 * NN + n] - wl, wl);
            acc += fmaf(sa[1], wrp[1 * NN + n] - wl, wl);
            acc += fmaf(sa[2], wrp[2 * NN + n] - wl, wl);
            acc += fmaf(sa[3], wrp[3 * NN + n] - wl, wl);
            wuo[n] = GAMMA * wuprev[(size_t)b * NN + n] + acc;
        }
    }
    __syncthreads();   // phase-2 reads of s_e4 done; safe to reuse as lr

    // ---- final r_t merge across the 8 waves (overlay lr into s_e4) ----
    float4* lr = s_e4;   // 8 waves * 4 heads * 16 cols = 512 float4
    if (row4 == 0) {
        #pragma unroll
        for (int r = 0; r < 4; r++) lr[wave * 64 + r * 16 + d4] = racc[r];
    }
    __syncthreads();
    if (t < 64) {
        const int r = t >> 4, dd = t & 15;
        float4 s = make_float4(0.f, 0.f, 0.f, 0.f);
        #pragma unroll
        for (int w = 0; w < 8; w++) {
            const float4 v = lr[w * 64 + r * 16 + dd];
            s.x += v.x; s.y += v.y; s.z += v.z; s.w += v.w;
        }
        const float inv = zi[r];
        const float4 rt = make_float4(s.x * inv, s.y * inv, s.z * inv, s.w * inv);
        *(float4*)(out + OUT_RT + (size_t)b * 256 + r * 64 + dd * 4) = rt;
        *(float4*)(out + (size_t)b * 768 + 512 + r * 64 + dd * 4) = rt;
    }
}

// ===================== host =====================
extern "C" void kernel_launch(void* const* d_in, const int* in_sizes, int n_in,
                              void* d_out, int out_size, void* d_ws, size_t ws_size,
                              hipStream_t stream)
{
    const float* x      = (const float*)d_in[0];
    const float* Mprev  = (const float*)d_in[1];
    const float* rprev  = (const float*)d_in[2];
    const float* hprev  = (const float*)d_in[3];
    const float* cprev  = (const float*)d_in[4];
    const float* wuprev = (const float*)d_in[5];
    const float* wrprev = (const float*)d_in[6];
    const float* Wih    = (const float*)d_in[7];
    const float* bih    = (const float*)d_in[8];
    const float* Whh    = (const float*)d_in[9];
    const float* bhh    = (const float*)d_in[10];
    const float* Wlin   = (const float*)d_in[11];
    const float* blin   = (const float*)d_in[12];
    float* out = (float*)d_out;
    float* ws  = (float*)d_ws;   // needs 1024*32*4 = 128 KB

    gemm_gates<<<dim3(32, 16), 256, 0, stream>>>(x, rprev, hprev, Wih, Whh, bih, bhh, out);
    lstm_pw<<<512, 256, 0, stream>>>(cprev, out);
    gemm_p<<<dim3(9, 16), 256, 0, stream>>>(Wlin, blin, out);
    kp_argmin_k<<<1024, 256, 0, stream>>>(wuprev, out, ws);
    fused_mem<<<1024, 512, 0, stream>>>(Mprev, wrprev, wuprev, out, ws);
}

// Round 12
// 389.866 us; speedup vs baseline: 1.0555x; 1.0555x over previous
//
#include <hip/hip_runtime.h>
#include <math.h>

// ---- problem constants ----
constexpr int BB   = 1024;   // batch
constexpr int NN   = 2048;   // memory slots
constexpr int DD   = 64;     // memory width
constexpr int RR   = 4;      // read heads
constexpr float GAMMA = 0.95f;

// ---- d_out flat layout (float elements, reference return order) ----
constexpr size_t OUT_OUT = 0;                                   // (B, 768)
constexpr size_t OUT_MT  = OUT_OUT + (size_t)BB * 768;          // (B, N, D)
constexpr size_t OUT_RT  = OUT_MT  + (size_t)BB * NN * DD;      // (B, 256)
constexpr size_t OUT_HT  = OUT_RT  + (size_t)BB * 256;          // (B, 512)
constexpr size_t OUT_CT  = OUT_HT  + (size_t)BB * 512;          // (B, 512)
constexpr size_t OUT_WU  = OUT_CT  + (size_t)BB * 512;          // (B, N)
constexpr size_t OUT_WR  = OUT_WU  + (size_t)BB * NN;           // (B, R*N)

// ---- scratch inside M_t region, per-batch slice (header read before overwrite) ----
constexpr int SLICE   = NN * DD;       // 131072
constexpr int OFF_A   = 0;             // a: 256 floats
constexpr int OFF_G   = 8456 + NN;     // gates: 2048
constexpr int OFF_P   = OFF_G + 2048;  // p: 520
constexpr int OFF_K   = OFF_P + 520;   // k: 256

// ---- d_ws per-batch stash: 32 floats ----
constexpr int WS_STRIDE = 32;
constexpr int WS_SA  = 0;   // sigma(alpha): 4
constexpr int WS_KN  = 4;   // knorm: 4
constexpr int WS_IDX = 16;  // idx4 (int bits): 4

__device__ __forceinline__ float sigmoidf_(float x) { return 1.0f / (1.0f + __expf(-x)); }

// VALU-pipe cross-lane add within each 16-lane row: x + dpp(x).
template<int CTRL>
__device__ __forceinline__ float dpp_add(float x) {
    int y = __builtin_amdgcn_update_dpp(0, __float_as_int(x), CTRL, 0xF, 0xF, false);
    return x + __int_as_float(y);
}
template<int CTRL>
__device__ __forceinline__ void dpp_add5(float& a, float& b, float& c, float& d, float& e) {
    a = dpp_add<CTRL>(a); b = dpp_add<CTRL>(b); c = dpp_add<CTRL>(c);
    d = dpp_add<CTRL>(d); e = dpp_add<CTRL>(e);
}

// ===================== GEMM 1: gates = [x,r_prev,h_prev] @ [W_ih|W_hh]^T + b =====================
// float4 staging + float4 LDS fragment reads; LDS rows padded to 68 floats.
__global__ __launch_bounds__(256) void gemm_gates(
    const float* __restrict__ x, const float* __restrict__ rprev, const float* __restrict__ hprev,
    const float* __restrict__ Wih, const float* __restrict__ Whh,
    const float* __restrict__ bih, const float* __restrict__ bhh,
    float* __restrict__ out)
{
    __shared__ float As[16][68];
    __shared__ float Bs[16][68];
    const int t = threadIdx.x;
    const int row0 = blockIdx.y * 64, col0 = blockIdx.x * 64;
    const int tx = t & 15, ty = t >> 4;
    const int li = t >> 2;            // 0..63: tile row / col index for staging
    const int kq = (t & 3) * 4;       // 0,4,8,12: k-quad within 16-wide k-tile
    float acc[4][4] = {};

    for (int k0 = 0; k0 < 1024; k0 += 16) {
        const int k = k0 + kq;
        {
            const int row = row0 + li;
            float4 av;
            if (k < 256)      av = *(const float4*)(x + row * 256 + k);
            else if (k < 512) av = *(const float4*)(rprev + row * 256 + (k - 256));
            else              av = *(const float4*)(hprev + row * 512 + (k - 512));
            As[kq + 0][li] = av.x; As[kq + 1][li] = av.y;
            As[kq + 2][li] = av.z; As[kq + 3][li] = av.w;
        }
        {
            const int j = col0 + li;
            const float4 bv = (k < 512) ? *(const float4*)(Wih + j * 512 + k)
                                        : *(const float4*)(Whh + j * 512 + (k - 512));
            Bs[kq + 0][li] = bv.x; Bs[kq + 1][li] = bv.y;
            Bs[kq + 2][li] = bv.z; Bs[kq + 3][li] = bv.w;
        }
        __syncthreads();
        #pragma unroll
        for (int kk = 0; kk < 16; kk++) {
            const float4 a4 = *(const float4*)&As[kk][ty * 4];
            const float4 b4 = *(const float4*)&Bs[kk][tx * 4];
            acc[0][0] += a4.x * b4.x; acc[0][1] += a4.x * b4.y; acc[0][2] += a4.x * b4.z; acc[0][3] += a4.x * b4.w;
            acc[1][0] += a4.y * b4.x; acc[1][1] += a4.y * b4.y; acc[1][2] += a4.y * b4.z; acc[1][3] += a4.y * b4.w;
            acc[2][0] += a4.z * b4.x; acc[2][1] += a4.z * b4.y; acc[2][2] += a4.z * b4.z; acc[2][3] += a4.z * b4.w;
            acc[3][0] += a4.w * b4.x; acc[3][1] += a4.w * b4.y; acc[3][2] += a4.w * b4.z; acc[3][3] += a4.w * b4.w;
        }
        __syncthreads();
    }
    float* mt = out + OUT_MT;
    #pragma unroll
    for (int ci = 0; ci < 4; ci++) {
        int row = row0 + ty * 4 + ci;
        #pragma unroll
        for (int cj = 0; cj < 4; cj++) {
            int col = col0 + tx * 4 + cj;
            mt[(size_t)row * SLICE + OFF_G + col] = acc[ci][cj] + bih[col] + bhh[col];
        }
    }
}

// ===================== LSTM pointwise (float4) =====================
__global__ __launch_bounds__(256) void lstm_pw(const float* __restrict__ cprev, float* __restrict__ out)
{
    const size_t e0 = ((size_t)blockIdx.x * 256 + threadIdx.x) * 4;  // 0 .. B*512-4
    const int b = (int)(e0 >> 9), j = (int)(e0 & 511);
    const float* g = out + OUT_MT + (size_t)b * SLICE + OFF_G;
    const float4 ig = *(const float4*)(g + j);
    const float4 fg = *(const float4*)(g + 512 + j);
    const float4 gg = *(const float4*)(g + 1024 + j);
    const float4 og = *(const float4*)(g + 1536 + j);
    const float4 cp = *(const float4*)(cprev + e0);
    float4 c, h;
    c.x = sigmoidf_(fg.x) * cp.x + sigmoidf_(ig.x) * tanhf(gg.x);
    c.y = sigmoidf_(fg.y) * cp.y + sigmoidf_(ig.y) * tanhf(gg.y);
    c.z = sigmoidf_(fg.z) * cp.z + sigmoidf_(ig.z) * tanhf(gg.z);
    c.w = sigmoidf_(fg.w) * cp.w + sigmoidf_(ig.w) * tanhf(gg.w);
    h.x = sigmoidf_(og.x) * tanhf(c.x);
    h.y = sigmoidf_(og.y) * tanhf(c.y);
    h.z = sigmoidf_(og.z) * tanhf(c.z);
    h.w = sigmoidf_(og.w) * tanhf(c.w);
    *(float4*)(out + OUT_CT + e0) = c;
    *(float4*)(out + OUT_HT + e0) = h;
    *(float4*)(out + (size_t)b * 768 + j) = h;
}

// ===================== GEMM 2: p = h_t @ W_lin^T + b_lin  (1024 x 516, K=512) =====================
__global__ __launch_bounds__(256) void gemm_p(
    const float* __restrict__ Wlin, const float* __restrict__ blin, float* __restrict__ out)
{
    __shared__ float As[16][68];
    __shared__ float Bs[16][68];
    const int t = threadIdx.x;
    const int row0 = blockIdx.y * 64, col0 = blockIdx.x * 64;
    const int tx = t & 15, ty = t >> 4;
    const int li = t >> 2;
    const int kq = (t & 3) * 4;
    const float* ht = out + OUT_HT;
    float acc[4][4] = {};

    for (int k0 = 0; k0 < 512; k0 += 16) {
        const int k = k0 + kq;
        {
            const int row = row0 + li;
            const float4 av = *(const float4*)(ht + (size_t)row * 512 + k);
            As[kq + 0][li] = av.x; As[kq + 1][li] = av.y;
            As[kq + 2][li] = av.z; As[kq + 3][li] = av.w;
        }
        {
            const int j = col0 + li;
            float4 bv = make_float4(0.f, 0.f, 0.f, 0.f);
            if (j < 516) bv = *(const float4*)(Wlin + j * 512 + k);
            Bs[kq + 0][li] = bv.x; Bs[kq + 1][li] = bv.y;
            Bs[kq + 2][li] = bv.z; Bs[kq + 3][li] = bv.w;
        }
        __syncthreads();
        #pragma unroll
        for (int kk = 0; kk < 16; kk++) {
            const float4 a4 = *(const float4*)&As[kk][ty * 4];
            const float4 b4 = *(const float4*)&Bs[kk][tx * 4];
            acc[0][0] += a4.x * b4.x; acc[0][1] += a4.x * b4.y; acc[0][2] += a4.x * b4.z; acc[0][3] += a4.x * b4.w;
            acc[1][0] += a4.y * b4.x; acc[1][1] += a4.y * b4.y; acc[1][2] += a4.y * b4.z; acc[1][3] += a4.y * b4.w;
            acc[2][0] += a4.z * b4.x; acc[2][1] += a4.z * b4.y; acc[2][2] += a4.z * b4.z; acc[2][3] += a4.z * b4.w;
            acc[3][0] += a4.w * b4.x; acc[3][1] += a4.w * b4.y; acc[3][2] += a4.w * b4.z; acc[3][3] += a4.w * b4.w;
        }
        __syncthreads();
    }
    float* mt = out + OUT_MT;
    #pragma unroll
    for (int ci = 0; ci < 4; ci++) {
        int row = row0 + ty * 4 + ci;
        #pragma unroll
        for (int cj = 0; cj < 4; cj++) {
            int col = col0 + tx * 4 + cj;
            if (col < 516)
                mt[(size_t)row * SLICE + OFF_P + col] = acc[ci][cj] + blin[col];
        }
    }
}

// ===================== k/a/sigma_alpha/knorm + argmin4, fused ==========
__global__ __launch_bounds__(256) void kp_argmin_k(
    const float* __restrict__ wuprev, float* __restrict__ out, float* __restrict__ ws)
{
    const int b = blockIdx.x, t = threadIdx.x;
    float* mt = out + OUT_MT;
    const size_t sl = (size_t)b * SLICE;
    float* wsb = ws + (size_t)b * WS_STRIDE;

    // ---- part 1: k, a, sigma(alpha), ||k|| ----
    {
        const float* p = mt + sl + OFF_P;
        const int r = t >> 6, d = t & 63;
        float kv = tanhf(p[r * 64 + d]);
        float av = tanhf(p[256 + r * 64 + d]);
        mt[sl + OFF_K + r * 64 + d] = kv;
        mt[sl + OFF_A + r * 64 + d] = av;
        float s2 = kv * kv;
        #pragma unroll
        for (int off = 1; off < 64; off <<= 1) s2 += __shfl_xor(s2, off);
        if (d == 0) wsb[WS_KN + r] = sqrtf(s2);
        if (t < 4) wsb[WS_SA + t] = sigmoidf_(p[512 + t]);
    }

    // ---- part 2: 4 smallest wu_prev indices (tie -> larger index) ----
    __shared__ float sval[256];
    __shared__ int   sidx[256];
    __shared__ int   chosen[4];
    float wu8[8];
    #pragma unroll
    for (int i = 0; i < 8; i++) wu8[i] = wuprev[(size_t)b * NN + t + i * 256];

    for (int it = 0; it < 4; it++) {
        float bv = 3.4e38f; int bi = -1;
        #pragma unroll
        for (int i = 0; i < 8; i++) {
            int n = t + i * 256;
            bool skip = false;
            for (int j = 0; j < it; j++) skip = skip || (n == chosen[j]);
            float v = wu8[i];
            if (!skip && (v < bv || (v == bv && n > bi))) { bv = v; bi = n; }
        }
        sval[t] = bv; sidx[t] = bi;
        __syncthreads();
        for (int s = 128; s; s >>= 1) {
            if (t < s) {
                float v2 = sval[t + s]; int i2 = sidx[t + s];
                if (v2 < sval[t] || (v2 == sval[t] && i2 > sidx[t])) { sval[t] = v2; sidx[t] = i2; }
            }
            __syncthreads();
        }
        if (t == 0) chosen[it] = sidx[0];
        __syncthreads();
    }
    if (t < 4)
        ((int*)wsb)[WS_IDX + t] = chosen[t];
}

// ===================== FUSED memory pass + softmax finalize =====================
// One block per batch (512 thr = 8 waves). Single M_prev read, single M_t write.
// Software-pipelined m4 prefetch; Z recomputed in phase 2 from the LDS e-buffer.
__global__ __launch_bounds__(512) void fused_mem(
    const float* __restrict__ Mprev, const float* __restrict__ wrprev,
    const float* __restrict__ wuprev,
    float* __restrict__ out, const float* __restrict__ ws)
{
    const int b = blockIdx.x, t = threadIdx.x;
    const int wave = t >> 6, lane = t & 63;
    const int row4 = lane >> 4, d4 = lane & 15;
    float* mt = out + OUT_MT;
    const size_t sl = (size_t)b * SLICE;
    const float* wsb = ws + (size_t)b * WS_STRIDE;

    __shared__ float4 s_e4[NN];     // 32 KB: e[n][r]; reused as lr in final merge
    __shared__ float  lz[8][4];     // per-wave partial Z

    // ---- header loads (sa/rck/id4 are wave-uniform -> SGPRs) ----
    float4 k4[4], a4[4]; float sa[4], rck[4]; int id4[4];
    #pragma unroll
    for (int r = 0; r < 4; r++) {
        k4[r] = *(const float4*)(mt + sl + OFF_K + r * 64 + d4 * 4);
        a4[r] = *(const float4*)(mt + sl + OFF_A + r * 64 + d4 * 4);
        sa[r]  = wsb[WS_SA + r];
        rck[r] = 1.0f / wsb[WS_KN + r];
        id4[r] = ((const int*)wsb)[WS_IDX + r];
    }
    __syncthreads();   // header fully read before any M_t row is overwritten

    const float* wrp = wrprev + (size_t)b * (RR * NN);
    const int kill = id4[0];
    const size_t mbase = (size_t)b * NN * DD + (size_t)(d4 * 4);

    float4 racc[4];
    #pragma unroll
    for (int r = 0; r < 4; r++) racc[r] = make_float4(0.f, 0.f, 0.f, 0.f);

    // prologue: load first row
    float4 m4 = *(const float4*)(Mprev + mbase + (size_t)(wave * 4 + row4) * DD);

    for (int it = 0; it < 64; it++) {
        const int n = it * 32 + wave * 4 + row4;
        const int nn = (n + 32) & (NN - 1);            // wrapped prefetch index (last iter harmless)
        const float4 m4n = *(const float4*)(Mprev + mbase + (size_t)nn * DD);  // prefetch next
        const float w0 = wrp[0 * NN + n];
        const float w1 = wrp[1 * NN + n];
        const float w2 = wrp[2 * NN + n];
        const float w3 = wrp[3 * NN + n];

        float nrm = m4.x * m4.x + m4.y * m4.y + m4.z * m4.z + m4.w * m4.w;
        float ip0 = k4[0].x * m4.x + k4[0].y * m4.y + k4[0].z * m4.z + k4[0].w * m4.w;
        float ip1 = k4[1].x * m4.x + k4[1].y * m4.y + k4[1].z * m4.z + k4[1].w * m4.w;
        float ip2 = k4[2].x * m4.x + k4[2].y * m4.y + k4[2].z * m4.z + k4[2].w * m4.w;
        float ip3 = k4[3].x * m4.x + k4[3].y * m4.y + k4[3].z * m4.z + k4[3].w * m4.w;
        // 16-lane reduce+broadcast on the VALU pipe (no DS traffic)
        dpp_add5<0xB1>(nrm, ip0, ip1, ip2, ip3);   // quad_perm xor1
        dpp_add5<0x4E>(nrm, ip0, ip1, ip2, ip3);   // quad_perm xor2
        dpp_add5<0x124>(nrm, ip0, ip1, ip2, ip3);  // row_ror:4
        dpp_add5<0x128>(nrm, ip0, ip1, ip2, ip3);  // row_ror:8

        const float rsn = rsqrtf(fmaxf(nrm, 1e-30f));
        const float e0 = __expf(ip0 * rck[0] * rsn);
        const float e1 = __expf(ip1 * rck[1] * rsn);
        const float e2 = __expf(ip2 * rck[2] * rsn);
        const float e3 = __expf(ip3 * rck[3] * rsn);
        if (d4 == 0) s_e4[n] = make_float4(e0, e1, e2, e3);

        // M_t row:  ww = sa*wrp + (1-sa)*wlu  ==  fma(sa, wrp - wlu, wlu)
        const float wlu = (n == id4[0] || n == id4[1] || n == id4[2] || n == id4[3]) ? 1.0f : 0.0f;
        float4 mtv = m4;
        if (n == kill) { mtv.x = 0.f; mtv.y = 0.f; mtv.z = 0.f; mtv.w = 0.f; }
        const float ww0 = fmaf(sa[0], w0 - wlu, wlu);
        const float ww1 = fmaf(sa[1], w1 - wlu, wlu);
        const float ww2 = fmaf(sa[2], w2 - wlu, wlu);
        const float ww3 = fmaf(sa[3], w3 - wlu, wlu);
        mtv.x += ww0 * a4[0].x + ww1 * a4[1].x + ww2 * a4[2].x + ww3 * a4[3].x;
        mtv.y += ww0 * a4[0].y + ww1 * a4[1].y + ww2 * a4[2].y + ww3 * a4[3].y;
        mtv.z += ww0 * a4[0].z + ww1 * a4[1].z + ww2 * a4[2].z + ww3 * a4[3].z;
        mtv.w += ww0 * a4[0].w + ww1 * a4[1].w + ww2 * a4[2].w + ww3 * a4[3].w;
        *(float4*)(mt + sl + (size_t)n * DD + d4 * 4) = mtv;

        // raw-softmax accumulation of r_t numerator
        racc[0].x += e0 * mtv.x; racc[0].y += e0 * mtv.y; racc[0].z += e0 * mtv.z; racc[0].w += e0 * mtv.w;
        racc[1].x += e1 * mtv.x; racc[1].y += e1 * mtv.y; racc[1].z += e1 * mtv.z; racc[1].w += e1 * mtv.w;
        racc[2].x += e2 * mtv.x; racc[2].y += e2 * mtv.y; racc[2].z += e2 * mtv.z; racc[2].w += e2 * mtv.w;
        racc[3].x += e3 * mtv.x; racc[3].y += e3 * mtv.y; racc[3].z += e3 * mtv.z; racc[3].w += e3 * mtv.w;

        m4 = m4n;   // rotate pipeline
    }

    // merge racc across the 4 row-groups within the wave (lane bits 4,5)
    #pragma unroll
    for (int off = 16; off < 64; off <<= 1) {
        #pragma unroll
        for (int r = 0; r < 4; r++) {
            racc[r].x += __shfl_xor(racc[r].x, off);
            racc[r].y += __shfl_xor(racc[r].y, off);
            racc[r].z += __shfl_xor(racc[r].z, off);
            racc[r].w += __shfl_xor(racc[r].w, off);
        }
    }
    __syncthreads();   // s_e4 now visible block-wide

    // ---- Z from s_e4 (wave shuffle reduce + 8-wave LDS merge) ----
    float z0 = 0.f, z1 = 0.f, z2 = 0.f, z3 = 0.f;
    #pragma unroll
    for (int i = 0; i < 4; i++) {
        const float4 e4 = s_e4[i * 512 + t];
        z0 += e4.x; z1 += e4.y; z2 += e4.z; z3 += e4.w;
    }
    #pragma unroll
    for (int off = 1; off < 64; off <<= 1) {
        z0 += __shfl_xor(z0, off); z1 += __shfl_xor(z1, off);
        z2 += __shfl_xor(z2, off); z3 += __shfl_xor(z3, off);
    }
    if (lane == 0) { lz[wave][0] = z0; lz[wave][1] = z1; lz[wave][2] = z2; lz[wave][3] = z3; }
    __syncthreads();
    float zi[4];
    #pragma unroll
    for (int r = 0; r < 4; r++) {
        float Z = 0.f;
        #pragma unroll
        for (int w = 0; w < 8; w++) Z += lz[w][r];
        zi[r] = 1.0f / Z;
    }

    // ---- phase 2: wr_t and wu_t (streaming; e from LDS) ----
    {
        float* wro = out + OUT_WR + (size_t)b * (RR * NN);
        float* wuo = out + OUT_WU + (size_t)b * NN;
        #pragma unroll
        for (int i = 0; i < 4; i++) {
            const int n = i * 512 + t;
            const float4 e4 = s_e4[n];
            const float wl = (n == id4[0] || n == id4[1] || n == id4[2] || n == id4[3]) ? 1.0f : 0.0f;
            const float wv0 = e4.x * zi[0], wv1 = e4.y * zi[1], wv2 = e4.z * zi[2], wv3 = e4.w * zi[3];
            wro[0 * NN + n] = wv0; wro[1 * NN + n] = wv1;
            wro[2 * NN + n] = wv2; wro[3 * NN + n] = wv3;
            float acc = wv0 + wv1 + wv2 + wv3;
            acc += fmaf(sa[0], wrp[0 * NN + n] - wl, wl);
            acc += fmaf(sa[1], wrp[1 * NN + n] - wl, wl);
            acc += fmaf(sa[2], wrp[2 * NN + n] - wl, wl);
            acc += fmaf(sa[3], wrp[3 * NN + n] - wl, wl);
            wuo[n] = GAMMA * wuprev[(size_t)b * NN + n] + acc;
        }
    }
    __syncthreads();   // phase-2 reads of s_e4 done; safe to reuse as lr

    // ---- final r_t merge across the 8 waves (overlay lr into s_e4) ----
    float4* lr = s_e4;   // 8 waves * 4 heads * 16 cols = 512 float4
    if (row4 == 0) {
        #pragma unroll
        for (int r = 0; r < 4; r++) lr[wave * 64 + r * 16 + d4] = racc[r];
    }
    __syncthreads();
    if (t < 64) {
        const int r = t >> 4, dd = t & 15;
        float4 s = make_float4(0.f, 0.f, 0.f, 0.f);
        #pragma unroll
        for (int w = 0; w < 8; w++) {
            const float4 v = lr[w * 64 + r * 16 + dd];
            s.x += v.x; s.y += v.y; s.z += v.z; s.w += v.w;
        }
        const float inv = zi[r];
        const float4 rt = make_float4(s.x * inv, s.y * inv, s.z * inv, s.w * inv);
        *(float4*)(out + OUT_RT + (size_t)b * 256 + r * 64 + dd * 4) = rt;
        *(float4*)(out + (size_t)b * 768 + 512 + r * 64 + dd * 4) = rt;
    }
}

// ===================== host =====================
extern "C" void kernel_launch(void* const* d_in, const int* in_sizes, int n_in,
                              void* d_out, int out_size, void* d_ws, size_t ws_size,
                              hipStream_t stream)
{
    const float* x      = (const float*)d_in[0];
    const float* Mprev  = (const float*)d_in[1];
    const float* rprev  = (const float*)d_in[2];
    const float* hprev  = (const float*)d_in[3];
    const float* cprev  = (const float*)d_in[4];
    const float* wuprev = (const float*)d_in[5];
    const float* wrprev = (const float*)d_in[6];
    const float* Wih    = (const float*)d_in[7];
    const float* bih    = (const float*)d_in[8];
    const float* Whh    = (const float*)d_in[9];
    const float* bhh    = (const float*)d_in[10];
    const float* Wlin   = (const float*)d_in[11];
    const float* blin   = (const float*)d_in[12];
    float* out = (float*)d_out;
    float* ws  = (float*)d_ws;   // needs 1024*32*4 = 128 KB

    gemm_gates<<<dim3(32, 16), 256, 0, stream>>>(x, rprev, hprev, Wih, Whh, bih, bhh, out);
    lstm_pw<<<512, 256, 0, stream>>>(cprev, out);
    gemm_p<<<dim3(9, 16), 256, 0, stream>>>(Wlin, blin, out);
    kp_argmin_k<<<1024, 256, 0, stream>>>(wuprev, out, ws);
    fused_mem<<<1024, 512, 0, stream>>>(Mprev, wrprev, wuprev, out, ws);
}

// Round 13
// 324.232 us; speedup vs baseline: 1.2692x; 1.2024x over previous
//
#include <hip/hip_runtime.h>
#include <math.h>

// ---- problem constants ----
constexpr int BB   = 1024;   // batch
constexpr int NN   = 2048;   // memory slots
constexpr int DD   = 64;     // memory width
constexpr int RR   = 4;      // read heads
constexpr float GAMMA = 0.95f;

// ---- d_out flat layout (float elements, reference return order) ----
constexpr size_t OUT_OUT = 0;                                   // (B, 768)
constexpr size_t OUT_MT  = OUT_OUT + (size_t)BB * 768;          // (B, N, D)
constexpr size_t OUT_RT  = OUT_MT  + (size_t)BB * NN * DD;      // (B, 256)
constexpr size_t OUT_HT  = OUT_RT  + (size_t)BB * 256;          // (B, 512)
constexpr size_t OUT_CT  = OUT_HT  + (size_t)BB * 512;          // (B, 512)
constexpr size_t OUT_WU  = OUT_CT  + (size_t)BB * 512;          // (B, N)
constexpr size_t OUT_WR  = OUT_WU  + (size_t)BB * NN;           // (B, R*N)

// ---- scratch inside M_t region, per-batch slice (header read before overwrite) ----
constexpr int SLICE   = NN * DD;       // 131072
constexpr int OFF_A   = 0;             // a: 256 floats
constexpr int OFF_G   = 8456 + NN;     // gates: 2048
constexpr int OFF_P   = OFF_G + 2048;  // p: 520
constexpr int OFF_K   = OFF_P + 520;   // k: 256

// bf16 operand stashes (dead scratch until fused_mem overwrites):
//   A_bf16 [1024 rows][1024 k]  (2 MB) lives at out+OUT_WU
//   W_bf16 [2048 rows][1024 k]  (4 MB) lives at out+OUT_WR

// ---- d_ws per-batch stash: 32 floats ----
constexpr int WS_STRIDE = 32;
constexpr int WS_SA  = 0;   // sigma(alpha): 4
constexpr int WS_KN  = 4;   // knorm: 4
constexpr int WS_IDX = 16;  // idx4 (int bits): 4

__device__ __forceinline__ float sigmoidf_(float x) { return 1.0f / (1.0f + __expf(-x)); }

typedef short short8 __attribute__((ext_vector_type(8)));
typedef float f32x4  __attribute__((ext_vector_type(4)));

// pack two f32 into one dword of 2 bf16 (round-to-nearest-even)
__device__ __forceinline__ unsigned bf16pack2(float a, float b) {
    unsigned ua = __float_as_uint(a), ub = __float_as_uint(b);
    ua = (ua + 0x7FFFu + ((ua >> 16) & 1u)) >> 16;
    ub = (ub + 0x7FFFu + ((ub >> 16) & 1u)) >> 16;
    return ua | (ub << 16);
}

// VALU-pipe cross-lane add within each 16-lane row: x + dpp(x).
template<int CTRL>
__device__ __forceinline__ float dpp_add(float x) {
    int y = __builtin_amdgcn_update_dpp(0, __float_as_int(x), CTRL, 0xF, 0xF, false);
    return x + __int_as_float(y);
}
template<int CTRL>
__device__ __forceinline__ void dpp_add5(float& a, float& b, float& c, float& d, float& e) {
    a = dpp_add<CTRL>(a); b = dpp_add<CTRL>(b); c = dpp_add<CTRL>(c);
    d = dpp_add<CTRL>(d); e = dpp_add<CTRL>(e);
}

// ===================== conv_A: [x|r_prev|h_prev] -> bf16 [1024][1024] =====================
__global__ __launch_bounds__(256) void conv_A(
    const float* __restrict__ x, const float* __restrict__ rprev, const float* __restrict__ hprev,
    unsigned* __restrict__ Abf)
{
    const int gid = blockIdx.x * 256 + threadIdx.x;   // 512 blocks -> 131072 threads
    const int e0 = gid * 8;
    const int row = e0 >> 10, col = e0 & 1023;
    float4 v0, v1;
    if (col < 256)      { const float* p = x + row * 256 + col;
                          v0 = *(const float4*)p; v1 = *(const float4*)(p + 4); }
    else if (col < 512) { const float* p = rprev + row * 256 + (col - 256);
                          v0 = *(const float4*)p; v1 = *(const float4*)(p + 4); }
    else                { const float* p = hprev + row * 512 + (col - 512);
                          v0 = *(const float4*)p; v1 = *(const float4*)(p + 4); }
    uint4 o;
    o.x = bf16pack2(v0.x, v0.y); o.y = bf16pack2(v0.z, v0.w);
    o.z = bf16pack2(v1.x, v1.y); o.w = bf16pack2(v1.z, v1.w);
    *(uint4*)(Abf + (size_t)row * 512 + (col >> 1)) = o;
}

// ===================== conv_W: [Wih|Whh] -> bf16 [2048][1024] =====================
__global__ __launch_bounds__(256) void conv_W(
    const float* __restrict__ Wih, const float* __restrict__ Whh, unsigned* __restrict__ Wbf)
{
    const int gid = blockIdx.x * 256 + threadIdx.x;   // 1024 blocks
    const int e0 = gid * 8;
    const int row = e0 >> 10, col = e0 & 1023;
    float4 v0, v1;
    if (col < 512) { const float* p = Wih + (size_t)row * 512 + col;
                     v0 = *(const float4*)p; v1 = *(const float4*)(p + 4); }
    else           { const float* p = Whh + (size_t)row * 512 + (col - 512);
                     v0 = *(const float4*)p; v1 = *(const float4*)(p + 4); }
    uint4 o;
    o.x = bf16pack2(v0.x, v0.y); o.y = bf16pack2(v0.z, v0.w);
    o.z = bf16pack2(v1.x, v1.y); o.w = bf16pack2(v1.z, v1.w);
    *(uint4*)(Wbf + (size_t)row * 512 + (col >> 1)) = o;
}

// ===================== GEMM 1 (bf16 MFMA, pre-converted operands) =====================
// 64x64 tile, 4 waves (2x2 quadrants), mfma_f32_16x16x32_bf16 2x2 per wave.
// Staging = 1 uint4 load + 1 b128 LDS write per operand per thread per K-step (no packing).
__global__ __launch_bounds__(256) void gemm_gates(
    const unsigned* __restrict__ Abf, const unsigned* __restrict__ Wbf,
    const float* __restrict__ bih, const float* __restrict__ bhh,
    float* __restrict__ out)
{
    __shared__ unsigned As[64][20];   // 64 rows x 40 bf16 (32 data + 8 pad)
    __shared__ unsigned Bs[64][20];
    const int t = threadIdx.x;
    const int wave = t >> 6, lane = t & 63;
    const int row0 = blockIdx.y * 64, col0 = blockIdx.x * 64;
    const int srow = t >> 2;          // staging row 0..63
    const int sk4  = (t & 3) * 4;     // u32 offset within 16-u32 k-chunk
    const int wm = wave >> 1, wn = wave & 1;
    const int lrow = lane & 15;
    const int ldw  = (lane >> 4) * 4;

    f32x4 acc00 = {0.f,0.f,0.f,0.f}, acc01 = {0.f,0.f,0.f,0.f};
    f32x4 acc10 = {0.f,0.f,0.f,0.f}, acc11 = {0.f,0.f,0.f,0.f};

    for (int k0 = 0; k0 < 512; k0 += 16) {   // k0 in u32 units (32 bf16 per step)
        const uint4 av = *(const uint4*)(Abf + (size_t)(row0 + srow) * 512 + k0 + sk4);
        const uint4 bv = *(const uint4*)(Wbf + (size_t)(col0 + srow) * 512 + k0 + sk4);
        __syncthreads();   // previous iteration's fragment reads complete
        *(uint4*)&As[srow][sk4] = av;
        *(uint4*)&Bs[srow][sk4] = bv;
        __syncthreads();   // tiles visible
        const short8 a0 = *(const short8*)&As[32 * wm + lrow][ldw];
        const short8 a1 = *(const short8*)&As[32 * wm + 16 + lrow][ldw];
        const short8 b0 = *(const short8*)&Bs[32 * wn + lrow][ldw];
        const short8 b1 = *(const short8*)&Bs[32 * wn + 16 + lrow][ldw];
        acc00 = __builtin_amdgcn_mfma_f32_16x16x32_bf16(a0, b0, acc00, 0, 0, 0);
        acc01 = __builtin_amdgcn_mfma_f32_16x16x32_bf16(a0, b1, acc01, 0, 0, 0);
        acc10 = __builtin_amdgcn_mfma_f32_16x16x32_bf16(a1, b0, acc10, 0, 0, 0);
        acc11 = __builtin_amdgcn_mfma_f32_16x16x32_bf16(a1, b1, acc11, 0, 0, 0);
    }

    // epilogue: C/D layout col = lane&15, row = (lane>>4)*4 + reg  (verified round 11)
    float* mt = out + OUT_MT;
    const int rbase = row0 + 32 * wm + (lane >> 4) * 4;
    #pragma unroll
    for (int ni = 0; ni < 2; ni++) {
        const int col = col0 + 32 * wn + 16 * ni + lrow;
        const float bb = bih[col] + bhh[col];
        #pragma unroll
        for (int reg = 0; reg < 4; reg++) {
            const float v0 = (ni == 0) ? acc00[reg] : acc01[reg];
            const float v1 = (ni == 0) ? acc10[reg] : acc11[reg];
            mt[(size_t)(rbase + reg) * SLICE + OFF_G + col] = v0 + bb;
            mt[(size_t)(rbase + 16 + reg) * SLICE + OFF_G + col] = v1 + bb;
        }
    }
}

// ===================== LSTM pointwise (float4) =====================
__global__ __launch_bounds__(256) void lstm_pw(const float* __restrict__ cprev, float* __restrict__ out)
{
    const size_t e0 = ((size_t)blockIdx.x * 256 + threadIdx.x) * 4;  // 0 .. B*512-4
    const int b = (int)(e0 >> 9), j = (int)(e0 & 511);
    const float* g = out + OUT_MT + (size_t)b * SLICE + OFF_G;
    const float4 ig = *(const float4*)(g + j);
    const float4 fg = *(const float4*)(g + 512 + j);
    const float4 gg = *(const float4*)(g + 1024 + j);
    const float4 og = *(const float4*)(g + 1536 + j);
    const float4 cp = *(const float4*)(cprev + e0);
    float4 c, h;
    c.x = sigmoidf_(fg.x) * cp.x + sigmoidf_(ig.x) * tanhf(gg.x);
    c.y = sigmoidf_(fg.y) * cp.y + sigmoidf_(ig.y) * tanhf(gg.y);
    c.z = sigmoidf_(fg.z) * cp.z + sigmoidf_(ig.z) * tanhf(gg.z);
    c.w = sigmoidf_(fg.w) * cp.w + sigmoidf_(ig.w) * tanhf(gg.w);
    h.x = sigmoidf_(og.x) * tanhf(c.x);
    h.y = sigmoidf_(og.y) * tanhf(c.y);
    h.z = sigmoidf_(og.z) * tanhf(c.z);
    h.w = sigmoidf_(og.w) * tanhf(c.w);
    *(float4*)(out + OUT_CT + e0) = c;
    *(float4*)(out + OUT_HT + e0) = h;
    *(float4*)(out + (size_t)b * 768 + j) = h;
}

// ===================== GEMM 2: p = h_t @ W_lin^T + b_lin  (1024 x 516, K=512) =====================
__global__ __launch_bounds__(256) void gemm_p(
    const float* __restrict__ Wlin, const float* __restrict__ blin, float* __restrict__ out)
{
    __shared__ float As[16][68];
    __shared__ float Bs[16][68];
    const int t = threadIdx.x;
    const int row0 = blockIdx.y * 64, col0 = blockIdx.x * 64;
    const int tx = t & 15, ty = t >> 4;
    const int li = t >> 2;
    const int kq = (t & 3) * 4;
    const float* ht = out + OUT_HT;
    float acc[4][4] = {};

    for (int k0 = 0; k0 < 512; k0 += 16) {
        const int k = k0 + kq;
        {
            const int row = row0 + li;
            const float4 av = *(const float4*)(ht + (size_t)row * 512 + k);
            As[kq + 0][li] = av.x; As[kq + 1][li] = av.y;
            As[kq + 2][li] = av.z; As[kq + 3][li] = av.w;
        }
        {
            const int j = col0 + li;
            float4 bv = make_float4(0.f, 0.f, 0.f, 0.f);
            if (j < 516) bv = *(const float4*)(Wlin + j * 512 + k);
            Bs[kq + 0][li] = bv.x; Bs[kq + 1][li] = bv.y;
            Bs[kq + 2][li] = bv.z; Bs[kq + 3][li] = bv.w;
        }
        __syncthreads();
        #pragma unroll
        for (int kk = 0; kk < 16; kk++) {
            const float4 a4 = *(const float4*)&As[kk][ty * 4];
            const float4 b4 = *(const float4*)&Bs[kk][tx * 4];
            acc[0][0] += a4.x * b4.x; acc[0][1] += a4.x * b4.y; acc[0][2] += a4.x * b4.z; acc[0][3] += a4.x * b4.w;
            acc[1][0] += a4.y * b4.x; acc[1][1] += a4.y * b4.y; acc[1][2] += a4.y * b4.z; acc[1][3] += a4.y * b4.w;
            acc[2][0] += a4.z * b4.x; acc[2][1] += a4.z * b4.y; acc[2][2] += a4.z * b4.z; acc[2][3] += a4.z * b4.w;
            acc[3][0] += a4.w * b4.x; acc[3][1] += a4.w * b4.y; acc[3][2] += a4.w * b4.z; acc[3][3] += a4.w * b4.w;
        }
        __syncthreads();
    }
    float* mt = out + OUT_MT;
    #pragma unroll
    for (int ci = 0; ci < 4; ci++) {
        int row = row0 + ty * 4 + ci;
        #pragma unroll
        for (int cj = 0; cj < 4; cj++) {
            int col = col0 + tx * 4 + cj;
            if (col < 516)
                mt[(size_t)row * SLICE + OFF_P + col] = acc[ci][cj] + blin[col];
        }
    }
}

// ===================== k/a/sigma_alpha/knorm + argmin4 (wave-shuffle reduction) ==========
__global__ __launch_bounds__(256) void kp_argmin_k(
    const float* __restrict__ wuprev, float* __restrict__ out, float* __restrict__ ws)
{
    const int b = blockIdx.x, t = threadIdx.x;
    const int wid = t >> 6, lane = t & 63;
    float* mt = out + OUT_MT;
    const size_t sl = (size_t)b * SLICE;
    float* wsb = ws + (size_t)b * WS_STRIDE;

    // ---- part 1: k, a, sigma(alpha), ||k|| ----
    {
        const float* p = mt + sl + OFF_P;
        const int r = t >> 6, d = t & 63;
        float kv = tanhf(p[r * 64 + d]);
        float av = tanhf(p[256 + r * 64 + d]);
        mt[sl + OFF_K + r * 64 + d] = kv;
        mt[sl + OFF_A + r * 64 + d] = av;
        float s2 = kv * kv;
        #pragma unroll
        for (int off = 1; off < 64; off <<= 1) s2 += __shfl_xor(s2, off);
        if (d == 0) wsb[WS_KN + r] = sqrtf(s2);
        if (t < 4) wsb[WS_SA + t] = sigmoidf_(p[512 + t]);
    }

    // ---- part 2: 4 smallest wu_prev indices (tie -> larger index) ----
    __shared__ float wv4[4];
    __shared__ int   wi4[4];
    __shared__ int   chosen[4];
    float wu8[8];
    #pragma unroll
    for (int i = 0; i < 8; i++) wu8[i] = wuprev[(size_t)b * NN + t + i * 256];

    for (int it = 0; it < 4; it++) {
        float bv = 3.4e38f; int bi = -1;
        #pragma unroll
        for (int i = 0; i < 8; i++) {
            int n = t + i * 256;
            bool skip = false;
            for (int j = 0; j < it; j++) skip = skip || (n == chosen[j]);
            float v = wu8[i];
            if (!skip && (v < bv || (v == bv && n > bi))) { bv = v; bi = n; }
        }
        // wave-level reduce on (val, idx)
        #pragma unroll
        for (int off = 1; off < 64; off <<= 1) {
            float v2 = __shfl_xor(bv, off);
            int   i2 = __shfl_xor(bi, off);
            if (v2 < bv || (v2 == bv && i2 > bi)) { bv = v2; bi = i2; }
        }
        if (lane == 0) { wv4[wid] = bv; wi4[wid] = bi; }
        __syncthreads();
        if (t == 0) {
            float fv = wv4[0]; int fi = wi4[0];
            #pragma unroll
            for (int w = 1; w < 4; w++) {
                float v2 = wv4[w]; int i2 = wi4[w];
                if (v2 < fv || (v2 == fv && i2 > fi)) { fv = v2; fi = i2; }
            }
            chosen[it] = fi;
        }
        __syncthreads();
    }
    if (t < 4)
        ((int*)wsb)[WS_IDX + t] = chosen[t];
}

// ===================== FUSED memory pass + softmax finalize =====================
// One block per batch (512 thr = 8 waves). Single M_prev read, single M_t write.
// Software-pipelined m4 prefetch; Z recomputed in phase 2 from the LDS e-buffer.
__global__ __launch_bounds__(512) void fused_mem(
    const float* __restrict__ Mprev, const float* __restrict__ wrprev,
    const float* __restrict__ wuprev,
    float* __restrict__ out, const float* __restrict__ ws)
{
    const int b = blockIdx.x, t = threadIdx.x;
    const int wave = t >> 6, lane = t & 63;
    const int row4 = lane >> 4, d4 = lane & 15;
    float* mt = out + OUT_MT;
    const size_t sl = (size_t)b * SLICE;
    const float* wsb = ws + (size_t)b * WS_STRIDE;

    __shared__ float4 s_e4[NN];     // 32 KB: e[n][r]; reused as lr in final merge
    __shared__ float  lz[8][4];     // per-wave partial Z

    // ---- header loads (sa/rck/id4 are wave-uniform -> SGPRs) ----
    float4 k4[4], a4[4]; float sa[4], rck[4]; int id4[4];
    #pragma unroll
    for (int r = 0; r < 4; r++) {
        k4[r] = *(const float4*)(mt + sl + OFF_K + r * 64 + d4 * 4);
        a4[r] = *(const float4*)(mt + sl + OFF_A + r * 64 + d4 * 4);
        sa[r]  = wsb[WS_SA + r];
        rck[r] = 1.0f / wsb[WS_KN + r];
        id4[r] = ((const int*)wsb)[WS_IDX + r];
    }
    __syncthreads();   // header fully read before any M_t row is overwritten

    const float* wrp = wrprev + (size_t)b * (RR * NN);
    const int kill = id4[0];
    const size_t mbase = (size_t)b * NN * DD + (size_t)(d4 * 4);

    float4 racc[4];
    #pragma unroll
    for (int r = 0; r < 4; r++) racc[r] = make_float4(0.f, 0.f, 0.f, 0.f);

    // prologue: load first row
    float4 m4 = *(const float4*)(Mprev + mbase + (size_t)(wave * 4 + row4) * DD);

    for (int it = 0; it < 64; it++) {
        const int n = it * 32 + wave * 4 + row4;
        const int nn = (n + 32) & (NN - 1);            // wrapped prefetch index (last iter harmless)
        const float4 m4n = *(const float4*)(Mprev + mbase + (size_t)nn * DD);  // prefetch next
        const float w0 = wrp[0 * NN + n];
        const float w1 = wrp[1 * NN + n];
        const float w2 = wrp[2 * NN + n];
        const float w3 = wrp[3 * NN + n];

        float nrm = m4.x * m4.x + m4.y * m4.y + m4.z * m4.z + m4.w * m4.w;
        float ip0 = k4[0].x * m4.x + k4[0].y * m4.y + k4[0].z * m4.z + k4[0].w * m4.w;
        float ip1 = k4[1].x * m4.x + k4[1].y * m4.y + k4[1].z * m4.z + k4[1].w * m4.w;
        float ip2 = k4[2].x * m4.x + k4[2].y * m4.y + k4[2].z * m4.z + k4[2].w * m4.w;
        float ip3 = k4[3].x * m4.x + k4[3].y * m4.y + k4[3].z * m4.z + k4[3].w * m4.w;
        // 16-lane reduce+broadcast on the VALU pipe (no DS traffic)
        dpp_add5<0xB1>(nrm, ip0, ip1, ip2, ip3);   // quad_perm xor1
        dpp_add5<0x4E>(nrm, ip0, ip1, ip2, ip3);   // quad_perm xor2
        dpp_add5<0x124>(nrm, ip0, ip1, ip2, ip3);  // row_ror:4
        dpp_add5<0x128>(nrm, ip0, ip1, ip2, ip3);  // row_ror:8

        const float rsn = rsqrtf(fmaxf(nrm, 1e-30f));
        const float e0 = __expf(ip0 * rck[0] * rsn);
        const float e1 = __expf(ip1 * rck[1] * rsn);
        const float e2 = __expf(ip2 * rck[2] * rsn);
        const float e3 = __expf(ip3 * rck[3] * rsn);
        if (d4 == 0) s_e4[n] = make_float4(e0, e1, e2, e3);

        // M_t row:  ww = sa*wrp + (1-sa)*wlu  ==  fma(sa, wrp - wlu, wlu)
        const float wlu = (n == id4[0] || n == id4[1] || n == id4[2] || n == id4[3]) ? 1.0f : 0.0f;
        float4 mtv = m4;
        if (n == kill) { mtv.x = 0.f; mtv.y = 0.f; mtv.z = 0.f; mtv.w = 0.f; }
        const float ww0 = fmaf(sa[0], w0 - wlu, wlu);
        const float ww1 = fmaf(sa[1], w1 - wlu, wlu);
        const float ww2 = fmaf(sa[2], w2 - wlu, wlu);
        const float ww3 = fmaf(sa[3], w3 - wlu, wlu);
        mtv.x += ww0 * a4[0].x + ww1 * a4[1].x + ww2 * a4[2].x + ww3 * a4[3].x;
        mtv.y += ww0 * a4[0].y + ww1 * a4[1].y + ww2 * a4[2].y + ww3 * a4[3].y;
        mtv.z += ww0 * a4[0].z + ww1 * a4[1].z + ww2 * a4[2].z + ww3 * a4[3].z;
        mtv.w += ww0 * a4[0].w + ww1 * a4[1].w + ww2 * a4[2].w + ww3 * a4[3].w;
        *(float4*)(mt + sl + (size_t)n * DD + d4 * 4) = mtv;

        // raw-softmax accumulation of r_t numerator
        racc[0].x += e0 * mtv.x; racc[0].y += e0 * mtv.y; racc[0].z += e0 * mtv.z; racc[0].w += e0 * mtv.w;
        racc[1].x += e1 * mtv.x; racc[1].y += e1 * mtv.y; racc[1].z += e1 * mtv.z; racc[1].w += e1 * mtv.w;
        racc[2].x += e2 * mtv.x; racc[2].y += e2 * mtv.y; racc[2].z += e2 * mtv.z; racc[2].w += e2 * mtv.w;
        racc[3].x += e3 * mtv.x; racc[3].y += e3 * mtv.y; racc[3].z += e3 * mtv.z; racc[3].w += e3 * mtv.w;

        m4 = m4n;   // rotate pipeline
    }

    // merge racc across the 4 row-groups within the wave (lane bits 4,5)
    #pragma unroll
    for (int off = 16; off < 64; off <<= 1) {
        #pragma unroll
        for (int r = 0; r < 4; r++) {
            racc[r].x += __shfl_xor(racc[r].x, off);
            racc[r].y += __shfl_xor(racc[r].y, off);
            racc[r].z += __shfl_xor(racc[r].z, off);
            racc[r].w += __shfl_xor(racc[r].w, off);
        }
    }
    __syncthreads();   // s_e4 now visible block-wide

    // ---- Z from s_e4 (wave shuffle reduce + 8-wave LDS merge) ----
    float z0 = 0.f, z1 = 0.f, z2 = 0.f, z3 = 0.f;
    #pragma unroll
    for (int i = 0; i < 4; i++) {
        const float4 e4 = s_e4[i * 512 + t];
        z0 += e4.x; z1 += e4.y; z2 += e4.z; z3 += e4.w;
    }
    #pragma unroll
    for (int off = 1; off < 64; off <<= 1) {
        z0 += __shfl_xor(z0, off); z1 += __shfl_xor(z1, off);
        z2 += __shfl_xor(z2, off); z3 += __shfl_xor(z3, off);
    }
    if (lane == 0) { lz[wave][0] = z0; lz[wave][1] = z1; lz[wave][2] = z2; lz[wave][3] = z3; }
    __syncthreads();
    float zi[4];
    #pragma unroll
    for (int r = 0; r < 4; r++) {
        float Z = 0.f;
        #pragma unroll
        for (int w = 0; w < 8; w++) Z += lz[w][r];
        zi[r] = 1.0f / Z;
    }

    // ---- phase 2: wr_t and wu_t (streaming; e from LDS) ----
    {
        float* wro = out + OUT_WR + (size_t)b * (RR * NN);
        float* wuo = out + OUT_WU + (size_t)b * NN;
        #pragma unroll
        for (int i = 0; i < 4; i++) {
            const int n = i * 512 + t;
            const float4 e4 = s_e4[n];
            const float wl = (n == id4[0] || n == id4[1] || n == id4[2] || n == id4[3]) ? 1.0f : 0.0f;
            const float wv0 = e4.x * zi[0], wv1 = e4.y * zi[1], wv2 = e4.z * zi[2], wv3 = e4.w * zi[3];
            wro[0 * NN + n] = wv0; wro[1 * NN + n] = wv1;
            wro[2 * NN + n] = wv2; wro[3 * NN + n] = wv3;
            float acc = wv0 + wv1 + wv2 + wv3;
            acc += fmaf(sa[0], wrp[0 * NN + n] - wl, wl);
            acc += fmaf(sa[1], wrp[1 * NN + n] - wl, wl);
            acc += fmaf(sa[2], wrp[2 * NN + n] - wl, wl);
            acc += fmaf(sa[3], wrp[3 * NN + n] - wl, wl);
            wuo[n] = GAMMA * wuprev[(size_t)b * NN + n] + acc;
        }
    }
    __syncthreads();   // phase-2 reads of s_e4 done; safe to reuse as lr

    // ---- final r_t merge across the 8 waves (overlay lr into s_e4) ----
    float4* lr = s_e4;   // 8 waves * 4 heads * 16 cols = 512 float4
    if (row4 == 0) {
        #pragma unroll
        for (int r = 0; r < 4; r++) lr[wave * 64 + r * 16 + d4] = racc[r];
    }
    __syncthreads();
    if (t < 64) {
        const int r = t >> 4, dd = t & 15;
        float4 s = make_float4(0.f, 0.f, 0.f, 0.f);
        #pragma unroll
        for (int w = 0; w < 8; w++) {
            const float4 v = lr[w * 64 + r * 16 + dd];
            s.x += v.x; s.y += v.y; s.z += v.z; s.w += v.w;
        }
        const float inv = zi[r];
        const float4 rt = make_float4(s.x * inv, s.y * inv, s.z * inv, s.w * inv);
        *(float4*)(out + OUT_RT + (size_t)b * 256 + r * 64 + dd * 4) = rt;
        *(float4*)(out + (size_t)b * 768 + 512 + r * 64 + dd * 4) = rt;
    }
}

// ===================== host =====================
extern "C" void kernel_launch(void* const* d_in, const int* in_sizes, int n_in,
                              void* d_out, int out_size, void* d_ws, size_t ws_size,
                              hipStream_t stream)
{
    const float* x      = (const float*)d_in[0];
    const float* Mprev  = (const float*)d_in[1];
    const float* rprev  = (const float*)d_in[2];
    const float* hprev  = (const float*)d_in[3];
    const float* cprev  = (const float*)d_in[4];
    const float* wuprev = (const float*)d_in[5];
    const float* wrprev = (const float*)d_in[6];
    const float* Wih    = (const float*)d_in[7];
    const float* bih    = (const float*)d_in[8];
    const float* Whh    = (const float*)d_in[9];
    const float* bhh    = (const float*)d_in[10];
    const float* Wlin   = (const float*)d_in[11];
    const float* blin   = (const float*)d_in[12];
    float* out = (float*)d_out;
    float* ws  = (float*)d_ws;   // needs 1024*32*4 = 128 KB

    unsigned* Abf = (unsigned*)(out + OUT_WU);   // 2 MB bf16 stash (overwritten by fused_mem)
    unsigned* Wbf = (unsigned*)(out + OUT_WR);   // 4 MB bf16 stash (overwritten by fused_mem)

    conv_A<<<512, 256, 0, stream>>>(x, rprev, hprev, Abf);
    conv_W<<<1024, 256, 0, stream>>>(Wih, Whh, Wbf);
    gemm_gates<<<dim3(32, 16), 256, 0, stream>>>(Abf, Wbf, bih, bhh, out);
    lstm_pw<<<512, 256, 0, stream>>>(cprev, out);
    gemm_p<<<dim3(9, 16), 256, 0, stream>>>(Wlin, blin, out);
    kp_argmin_k<<<1024, 256, 0, stream>>>(wuprev, out, ws);
    fused_mem<<<1024, 512, 0, stream>>>(Mprev, wrprev, wuprev, out, ws);
}

// Round 14
// 287.276 us; speedup vs baseline: 1.4324x; 1.1286x over previous
//
#include <hip/hip_runtime.h>
#include <math.h>

// ---- problem constants ----
constexpr int BB   = 1024;   // batch
constexpr int NN   = 2048;   // memory slots
constexpr int DD   = 64;     // memory width
constexpr int RR   = 4;      // read heads
constexpr float GAMMA = 0.95f;

// ---- d_out flat layout (float elements, reference return order) ----
constexpr size_t OUT_OUT = 0;                                   // (B, 768)
constexpr size_t OUT_MT  = OUT_OUT + (size_t)BB * 768;          // (B, N, D)
constexpr size_t OUT_RT  = OUT_MT  + (size_t)BB * NN * DD;      // (B, 256)
constexpr size_t OUT_HT  = OUT_RT  + (size_t)BB * 256;          // (B, 512)
constexpr size_t OUT_CT  = OUT_HT  + (size_t)BB * 512;          // (B, 512)
constexpr size_t OUT_WU  = OUT_CT  + (size_t)BB * 512;          // (B, N)
constexpr size_t OUT_WR  = OUT_WU  + (size_t)BB * NN;           // (B, R*N)

// ---- scratch inside M_t region, per-batch slice (header read before overwrite) ----
constexpr int SLICE   = NN * DD;       // 131072
constexpr int OFF_G   = 8456 + NN;     // gates: 2048
constexpr int OFF_P   = OFF_G + 2048;  // p: 520   (rows 196..204 of M_t; read before loop)

// bf16 operand stashes (dead scratch until overwritten by later kernels):
//   A_bf16   [1024][1024]  (2 MB)   at out+OUT_WU
//   Wlin_bf16 [576][512]  (288 KB)  at out+OUT_WU + 4 MB
//   W_bf16   [2048][1024]  (4 MB)   at out+OUT_WR
//   h_bf16   [1024][512]   (1 MB)   at out+OUT_RT (overwritten by fused_mem r_t)

__device__ __forceinline__ float sigmoidf_(float x) { return 1.0f / (1.0f + __expf(-x)); }

typedef short short8 __attribute__((ext_vector_type(8)));
typedef float f32x4  __attribute__((ext_vector_type(4)));

// pack two f32 into one dword of 2 bf16 (round-to-nearest-even)
__device__ __forceinline__ unsigned bf16pack2(float a, float b) {
    unsigned ua = __float_as_uint(a), ub = __float_as_uint(b);
    ua = (ua + 0x7FFFu + ((ua >> 16) & 1u)) >> 16;
    ub = (ub + 0x7FFFu + ((ub >> 16) & 1u)) >> 16;
    return ua | (ub << 16);
}

// VALU-pipe cross-lane add within each 16-lane row: x + dpp(x).
template<int CTRL>
__device__ __forceinline__ float dpp_add(float x) {
    int y = __builtin_amdgcn_update_dpp(0, __float_as_int(x), CTRL, 0xF, 0xF, false);
    return x + __int_as_float(y);
}
template<int CTRL>
__device__ __forceinline__ void dpp_add5(float& a, float& b, float& c, float& d, float& e) {
    a = dpp_add<CTRL>(a); b = dpp_add<CTRL>(b); c = dpp_add<CTRL>(c);
    d = dpp_add<CTRL>(d); e = dpp_add<CTRL>(e);
}

// ===================== conv_all: f32 -> bf16 stashes (A, W, Wlin) =====================
__global__ __launch_bounds__(256) void conv_all(
    const float* __restrict__ x, const float* __restrict__ rprev, const float* __restrict__ hprev,
    const float* __restrict__ Wih, const float* __restrict__ Whh, const float* __restrict__ Wlin,
    unsigned* __restrict__ Abf, unsigned* __restrict__ Wbf, unsigned* __restrict__ Wlbf)
{
    const int bid = blockIdx.x;
    if (bid < 512) {
        // A = [x|r_prev|h_prev] -> [1024][1024] bf16
        const int gid = bid * 256 + threadIdx.x;
        const int e0 = gid * 8;
        const int row = e0 >> 10, col = e0 & 1023;
        float4 v0, v1;
        if (col < 256)      { const float* p = x + row * 256 + col;
                              v0 = *(const float4*)p; v1 = *(const float4*)(p + 4); }
        else if (col < 512) { const float* p = rprev + row * 256 + (col - 256);
                              v0 = *(const float4*)p; v1 = *(const float4*)(p + 4); }
        else                { const float* p = hprev + row * 512 + (col - 512);
                              v0 = *(const float4*)p; v1 = *(const float4*)(p + 4); }
        uint4 o;
        o.x = bf16pack2(v0.x, v0.y); o.y = bf16pack2(v0.z, v0.w);
        o.z = bf16pack2(v1.x, v1.y); o.w = bf16pack2(v1.z, v1.w);
        *(uint4*)(Abf + (size_t)row * 512 + (col >> 1)) = o;
    } else if (bid < 1536) {
        // W = [Wih|Whh] -> [2048][1024] bf16
        const int gid = (bid - 512) * 256 + threadIdx.x;
        const int e0 = gid * 8;
        const int row = e0 >> 10, col = e0 & 1023;
        float4 v0, v1;
        if (col < 512) { const float* p = Wih + (size_t)row * 512 + col;
                         v0 = *(const float4*)p; v1 = *(const float4*)(p + 4); }
        else           { const float* p = Whh + (size_t)row * 512 + (col - 512);
                         v0 = *(const float4*)p; v1 = *(const float4*)(p + 4); }
        uint4 o;
        o.x = bf16pack2(v0.x, v0.y); o.y = bf16pack2(v0.z, v0.w);
        o.z = bf16pack2(v1.x, v1.y); o.w = bf16pack2(v1.z, v1.w);
        *(uint4*)(Wbf + (size_t)row * 512 + (col >> 1)) = o;
    } else {
        // Wlin [516][512] -> bf16 (129 blocks x 256 thr x 8 elems = 264192 exact)
        const int gid = (bid - 1536) * 256 + threadIdx.x;
        const int e0 = gid * 8;
        const int row = e0 >> 9, col = e0 & 511;
        const float* p = Wlin + (size_t)row * 512 + col;
        const float4 v0 = *(const float4*)p, v1 = *(const float4*)(p + 4);
        uint4 o;
        o.x = bf16pack2(v0.x, v0.y); o.y = bf16pack2(v0.z, v0.w);
        o.z = bf16pack2(v1.x, v1.y); o.w = bf16pack2(v1.z, v1.w);
        *(uint4*)(Wlbf + (size_t)row * 256 + (col >> 1)) = o;
    }
}

// ===================== GEMM 1 (bf16 MFMA): gates = A @ W^T + b =====================
__global__ __launch_bounds__(256) void gemm_gates(
    const unsigned* __restrict__ Abf, const unsigned* __restrict__ Wbf,
    const float* __restrict__ bih, const float* __restrict__ bhh,
    float* __restrict__ out)
{
    __shared__ unsigned As[64][20];   // 64 rows x 40 bf16 (32 data + 8 pad)
    __shared__ unsigned Bs[64][20];
    const int t = threadIdx.x;
    const int wave = t >> 6, lane = t & 63;
    const int row0 = blockIdx.y * 64, col0 = blockIdx.x * 64;
    const int srow = t >> 2;
    const int sk4  = (t & 3) * 4;
    const int wm = wave >> 1, wn = wave & 1;
    const int lrow = lane & 15;
    const int ldw  = (lane >> 4) * 4;

    f32x4 acc00 = {0.f,0.f,0.f,0.f}, acc01 = {0.f,0.f,0.f,0.f};
    f32x4 acc10 = {0.f,0.f,0.f,0.f}, acc11 = {0.f,0.f,0.f,0.f};

    for (int k0 = 0; k0 < 512; k0 += 16) {   // u32 units: 32 bf16 per step
        const uint4 av = *(const uint4*)(Abf + (size_t)(row0 + srow) * 512 + k0 + sk4);
        const uint4 bv = *(const uint4*)(Wbf + (size_t)(col0 + srow) * 512 + k0 + sk4);
        __syncthreads();
        *(uint4*)&As[srow][sk4] = av;
        *(uint4*)&Bs[srow][sk4] = bv;
        __syncthreads();
        const short8 a0 = *(const short8*)&As[32 * wm + lrow][ldw];
        const short8 a1 = *(const short8*)&As[32 * wm + 16 + lrow][ldw];
        const short8 b0 = *(const short8*)&Bs[32 * wn + lrow][ldw];
        const short8 b1 = *(const short8*)&Bs[32 * wn + 16 + lrow][ldw];
        acc00 = __builtin_amdgcn_mfma_f32_16x16x32_bf16(a0, b0, acc00, 0, 0, 0);
        acc01 = __builtin_amdgcn_mfma_f32_16x16x32_bf16(a0, b1, acc01, 0, 0, 0);
        acc10 = __builtin_amdgcn_mfma_f32_16x16x32_bf16(a1, b0, acc10, 0, 0, 0);
        acc11 = __builtin_amdgcn_mfma_f32_16x16x32_bf16(a1, b1, acc11, 0, 0, 0);
    }

    float* mt = out + OUT_MT;
    const int rbase = row0 + 32 * wm + (lane >> 4) * 4;
    #pragma unroll
    for (int ni = 0; ni < 2; ni++) {
        const int col = col0 + 32 * wn + 16 * ni + lrow;
        const float bb = bih[col] + bhh[col];
        #pragma unroll
        for (int reg = 0; reg < 4; reg++) {
            const float v0 = (ni == 0) ? acc00[reg] : acc01[reg];
            const float v1 = (ni == 0) ? acc10[reg] : acc11[reg];
            mt[(size_t)(rbase + reg) * SLICE + OFF_G + col] = v0 + bb;
            mt[(size_t)(rbase + 16 + reg) * SLICE + OFF_G + col] = v1 + bb;
        }
    }
}

// ===================== LSTM pointwise (float4) + h bf16 stash =====================
__global__ __launch_bounds__(256) void lstm_pw(const float* __restrict__ cprev, float* __restrict__ out)
{
    const size_t e0 = ((size_t)blockIdx.x * 256 + threadIdx.x) * 4;  // 0 .. B*512-4
    const int b = (int)(e0 >> 9), j = (int)(e0 & 511);
    const float* g = out + OUT_MT + (size_t)b * SLICE + OFF_G;
    const float4 ig = *(const float4*)(g + j);
    const float4 fg = *(const float4*)(g + 512 + j);
    const float4 gg = *(const float4*)(g + 1024 + j);
    const float4 og = *(const float4*)(g + 1536 + j);
    const float4 cp = *(const float4*)(cprev + e0);
    float4 c, h;
    c.x = sigmoidf_(fg.x) * cp.x + sigmoidf_(ig.x) * tanhf(gg.x);
    c.y = sigmoidf_(fg.y) * cp.y + sigmoidf_(ig.y) * tanhf(gg.y);
    c.z = sigmoidf_(fg.z) * cp.z + sigmoidf_(ig.z) * tanhf(gg.z);
    c.w = sigmoidf_(fg.w) * cp.w + sigmoidf_(ig.w) * tanhf(gg.w);
    h.x = sigmoidf_(og.x) * tanhf(c.x);
    h.y = sigmoidf_(og.y) * tanhf(c.y);
    h.z = sigmoidf_(og.z) * tanhf(c.z);
    h.w = sigmoidf_(og.w) * tanhf(c.w);
    *(float4*)(out + OUT_CT + e0) = c;
    *(float4*)(out + OUT_HT + e0) = h;
    *(float4*)(out + (size_t)b * 768 + j) = h;
    // bf16 stash for gemm_p (lives in OUT_RT region, overwritten later by r_t)
    unsigned* hbf = (unsigned*)(out + OUT_RT);
    uint2 hp; hp.x = bf16pack2(h.x, h.y); hp.y = bf16pack2(h.z, h.w);
    *(uint2*)(hbf + (size_t)b * 256 + (j >> 1)) = hp;
}

// ===================== GEMM 2 (bf16 MFMA): p = h @ Wlin^T + b_lin =====================
__global__ __launch_bounds__(256) void gemm_p(
    const unsigned* __restrict__ Hbf, const unsigned* __restrict__ Wlbf,
    const float* __restrict__ blin, float* __restrict__ out)
{
    __shared__ unsigned As[64][20];
    __shared__ unsigned Bs[64][20];
    const int t = threadIdx.x;
    const int wave = t >> 6, lane = t & 63;
    const int row0 = blockIdx.y * 64, col0 = blockIdx.x * 64;
    const int srow = t >> 2;
    const int sk4  = (t & 3) * 4;
    const int wm = wave >> 1, wn = wave & 1;
    const int lrow = lane & 15;
    const int ldw  = (lane >> 4) * 4;

    f32x4 acc00 = {0.f,0.f,0.f,0.f}, acc01 = {0.f,0.f,0.f,0.f};
    f32x4 acc10 = {0.f,0.f,0.f,0.f}, acc11 = {0.f,0.f,0.f,0.f};

    for (int k0 = 0; k0 < 256; k0 += 16) {   // u32 units: K=512 bf16
        const uint4 av = *(const uint4*)(Hbf  + (size_t)(row0 + srow) * 256 + k0 + sk4);
        const uint4 bv = *(const uint4*)(Wlbf + (size_t)(col0 + srow) * 256 + k0 + sk4);
        __syncthreads();
        *(uint4*)&As[srow][sk4] = av;
        *(uint4*)&Bs[srow][sk4] = bv;
        __syncthreads();
        const short8 a0 = *(const short8*)&As[32 * wm + lrow][ldw];
        const short8 a1 = *(const short8*)&As[32 * wm + 16 + lrow][ldw];
        const short8 b0 = *(const short8*)&Bs[32 * wn + lrow][ldw];
        const short8 b1 = *(const short8*)&Bs[32 * wn + 16 + lrow][ldw];
        acc00 = __builtin_amdgcn_mfma_f32_16x16x32_bf16(a0, b0, acc00, 0, 0, 0);
        acc01 = __builtin_amdgcn_mfma_f32_16x16x32_bf16(a0, b1, acc01, 0, 0, 0);
        acc10 = __builtin_amdgcn_mfma_f32_16x16x32_bf16(a1, b0, acc10, 0, 0, 0);
        acc11 = __builtin_amdgcn_mfma_f32_16x16x32_bf16(a1, b1, acc11, 0, 0, 0);
    }

    float* mt = out + OUT_MT;
    const int rbase = row0 + 32 * wm + (lane >> 4) * 4;
    #pragma unroll
    for (int ni = 0; ni < 2; ni++) {
        const int col = col0 + 32 * wn + 16 * ni + lrow;
        if (col < 516) {
            const float bb = blin[col];
            #pragma unroll
            for (int reg = 0; reg < 4; reg++) {
                const float v0 = (ni == 0) ? acc00[reg] : acc01[reg];
                const float v1 = (ni == 0) ? acc10[reg] : acc11[reg];
                mt[(size_t)(rbase + reg) * SLICE + OFF_P + col] = v0 + bb;
                mt[(size_t)(rbase + 16 + reg) * SLICE + OFF_P + col] = v1 + bb;
            }
        }
    }
}

// ===================== FUSED: header (k/a/sa/rck/argmin) + memory pass + softmax ==========
// One block per batch (512 thr = 8 waves). Single M_prev read, single M_t write.
__global__ __launch_bounds__(512) void fused_mem(
    const float* __restrict__ Mprev, const float* __restrict__ wrprev,
    const float* __restrict__ wuprev, float* __restrict__ out)
{
    const int b = blockIdx.x, t = threadIdx.x;
    const int wave = t >> 6, lane = t & 63;
    const int row4 = lane >> 4, d4 = lane & 15;
    float* mt = out + OUT_MT;
    const size_t sl = (size_t)b * SLICE;

    __shared__ float4 s_e4[NN];     // 32 KB: e[n][r]; reused as lr in final merge
    __shared__ float  lz[8][4];
    __shared__ float  s_k[256], s_a[256];
    __shared__ float  s_sa[4], s_rck[4];
    __shared__ float  wvred[8];
    __shared__ int    wired[8];
    __shared__ int    chosen[4];

    // ---- header part 1: k, a, sigma(alpha), 1/||k|| from p (waves 0-3) ----
    {
        const float* p = mt + sl + OFF_P;
        if (t < 256) {
            const int r = t >> 6, d = t & 63;   // wave r handles head r
            const float kv = tanhf(p[r * 64 + d]);
            const float av = tanhf(p[256 + r * 64 + d]);
            s_k[t] = kv; s_a[t] = av;
            float s2 = kv * kv;
            #pragma unroll
            for (int off = 1; off < 64; off <<= 1) s2 += __shfl_xor(s2, off);
            if (d == 0) s_rck[r] = rsqrtf(s2);
            if (t < 4) s_sa[t] = sigmoidf_(p[512 + t]);
        }
    }

    // ---- header part 2: 4 smallest wu_prev indices (tie -> larger index) ----
    {
        float wu4[4];
        #pragma unroll
        for (int i = 0; i < 4; i++) wu4[i] = wuprev[(size_t)b * NN + t + i * 512];
        for (int it = 0; it < 4; it++) {
            float bv = 3.4e38f; int bi = -1;
            #pragma unroll
            for (int i = 0; i < 4; i++) {
                const int n = t + i * 512;
                bool skip = false;
                for (int j = 0; j < it; j++) skip = skip || (n == chosen[j]);
                const float v = wu4[i];
                if (!skip && (v < bv || (v == bv && n > bi))) { bv = v; bi = n; }
            }
            #pragma unroll
            for (int off = 1; off < 64; off <<= 1) {
                const float v2 = __shfl_xor(bv, off);
                const int   i2 = __shfl_xor(bi, off);
                if (v2 < bv || (v2 == bv && i2 > bi)) { bv = v2; bi = i2; }
            }
            if (lane == 0) { wvred[wave] = bv; wired[wave] = bi; }
            __syncthreads();
            if (t == 0) {
                float fv = wvred[0]; int fi = wired[0];
                #pragma unroll
                for (int w = 1; w < 8; w++) {
                    if (wvred[w] < fv || (wvred[w] == fv && wired[w] > fi)) { fv = wvred[w]; fi = wired[w]; }
                }
                chosen[it] = fi;
            }
            __syncthreads();
        }
    }

    // ---- gather header results (all LDS writes fenced by last sync above) ----
    float sa[4], rck[4]; int id4[4];
    float4 k4[4], a4[4];
    #pragma unroll
    for (int r = 0; r < 4; r++) {
        sa[r]  = s_sa[r];
        rck[r] = s_rck[r];
        id4[r] = chosen[r];
        k4[r] = *(const float4*)&s_k[r * 64 + d4 * 4];
        a4[r] = *(const float4*)&s_a[r * 64 + d4 * 4];
    }

    const float* wrp = wrprev + (size_t)b * (RR * NN);
    const int kill = id4[0];
    const size_t mbase = (size_t)b * NN * DD + (size_t)(d4 * 4);

    float4 racc[4];
    #pragma unroll
    for (int r = 0; r < 4; r++) racc[r] = make_float4(0.f, 0.f, 0.f, 0.f);

    // prologue: load first row
    float4 m4 = *(const float4*)(Mprev + mbase + (size_t)(wave * 4 + row4) * DD);

    for (int it = 0; it < 64; it++) {
        const int n = it * 32 + wave * 4 + row4;
        const int nn = (n + 32) & (NN - 1);
        const float4 m4n = *(const float4*)(Mprev + mbase + (size_t)nn * DD);  // prefetch next
        const float w0 = wrp[0 * NN + n];
        const float w1 = wrp[1 * NN + n];
        const float w2 = wrp[2 * NN + n];
        const float w3 = wrp[3 * NN + n];

        float nrm = m4.x * m4.x + m4.y * m4.y + m4.z * m4.z + m4.w * m4.w;
        float ip0 = k4[0].x * m4.x + k4[0].y * m4.y + k4[0].z * m4.z + k4[0].w * m4.w;
        float ip1 = k4[1].x * m4.x + k4[1].y * m4.y + k4[1].z * m4.z + k4[1].w * m4.w;
        float ip2 = k4[2].x * m4.x + k4[2].y * m4.y + k4[2].z * m4.z + k4[2].w * m4.w;
        float ip3 = k4[3].x * m4.x + k4[3].y * m4.y + k4[3].z * m4.z + k4[3].w * m4.w;
        dpp_add5<0xB1>(nrm, ip0, ip1, ip2, ip3);   // quad_perm xor1
        dpp_add5<0x4E>(nrm, ip0, ip1, ip2, ip3);   // quad_perm xor2
        dpp_add5<0x124>(nrm, ip0, ip1, ip2, ip3);  // row_ror:4
        dpp_add5<0x128>(nrm, ip0, ip1, ip2, ip3);  // row_ror:8

        const float rsn = rsqrtf(fmaxf(nrm, 1e-30f));
        const float e0 = __expf(ip0 * rck[0] * rsn);
        const float e1 = __expf(ip1 * rck[1] * rsn);
        const float e2 = __expf(ip2 * rck[2] * rsn);
        const float e3 = __expf(ip3 * rck[3] * rsn);
        if (d4 == 0) s_e4[n] = make_float4(e0, e1, e2, e3);

        const float wlu = (n == id4[0] || n == id4[1] || n == id4[2] || n == id4[3]) ? 1.0f : 0.0f;
        float4 mtv = m4;
        if (n == kill) { mtv.x = 0.f; mtv.y = 0.f; mtv.z = 0.f; mtv.w = 0.f; }
        const float ww0 = fmaf(sa[0], w0 - wlu, wlu);
        const float ww1 = fmaf(sa[1], w1 - wlu, wlu);
        const float ww2 = fmaf(sa[2], w2 - wlu, wlu);
        const float ww3 = fmaf(sa[3], w3 - wlu, wlu);
        mtv.x += ww0 * a4[0].x + ww1 * a4[1].x + ww2 * a4[2].x + ww3 * a4[3].x;
        mtv.y += ww0 * a4[0].y + ww1 * a4[1].y + ww2 * a4[2].y + ww3 * a4[3].y;
        mtv.z += ww0 * a4[0].z + ww1 * a4[1].z + ww2 * a4[2].z + ww3 * a4[3].z;
        mtv.w += ww0 * a4[0].w + ww1 * a4[1].w + ww2 * a4[2].w + ww3 * a4[3].w;
        *(float4*)(mt + sl + (size_t)n * DD + d4 * 4) = mtv;

        racc[0].x += e0 * mtv.x; racc[0].y += e0 * mtv.y; racc[0].z += e0 * mtv.z; racc[0].w += e0 * mtv.w;
        racc[1].x += e1 * mtv.x; racc[1].y += e1 * mtv.y; racc[1].z += e1 * mtv.z; racc[1].w += e1 * mtv.w;
        racc[2].x += e2 * mtv.x; racc[2].y += e2 * mtv.y; racc[2].z += e2 * mtv.z; racc[2].w += e2 * mtv.w;
        racc[3].x += e3 * mtv.x; racc[3].y += e3 * mtv.y; racc[3].z += e3 * mtv.z; racc[3].w += e3 * mtv.w;

        m4 = m4n;
    }

    // merge racc across the 4 row-groups within the wave
    #pragma unroll
    for (int off = 16; off < 64; off <<= 1) {
        #pragma unroll
        for (int r = 0; r < 4; r++) {
            racc[r].x += __shfl_xor(racc[r].x, off);
            racc[r].y += __shfl_xor(racc[r].y, off);
            racc[r].z += __shfl_xor(racc[r].z, off);
            racc[r].w += __shfl_xor(racc[r].w, off);
        }
    }
    __syncthreads();   // s_e4 now visible block-wide

    // ---- Z from s_e4 ----
    float z0 = 0.f, z1 = 0.f, z2 = 0.f, z3 = 0.f;
    #pragma unroll
    for (int i = 0; i < 4; i++) {
        const float4 e4 = s_e4[i * 512 + t];
        z0 += e4.x; z1 += e4.y; z2 += e4.z; z3 += e4.w;
    }
    #pragma unroll
    for (int off = 1; off < 64; off <<= 1) {
        z0 += __shfl_xor(z0, off); z1 += __shfl_xor(z1, off);
        z2 += __shfl_xor(z2, off); z3 += __shfl_xor(z3, off);
    }
    if (lane == 0) { lz[wave][0] = z0; lz[wave][1] = z1; lz[wave][2] = z2; lz[wave][3] = z3; }
    __syncthreads();
    float zi[4];
    #pragma unroll
    for (int r = 0; r < 4; r++) {
        float Z = 0.f;
        #pragma unroll
        for (int w = 0; w < 8; w++) Z += lz[w][r];
        zi[r] = 1.0f / Z;
    }

    // ---- phase 2: wr_t and wu_t ----
    {
        float* wro = out + OUT_WR + (size_t)b * (RR * NN);
        float* wuo = out + OUT_WU + (size_t)b * NN;
        #pragma unroll
        for (int i = 0; i < 4; i++) {
            const int n = i * 512 + t;
            const float4 e4 = s_e4[n];
            const float wl = (n == id4[0] || n == id4[1] || n == id4[2] || n == id4[3]) ? 1.0f : 0.0f;
            const float wv0 = e4.x * zi[0], wv1 = e4.y * zi[1], wv2 = e4.z * zi[2], wv3 = e4.w * zi[3];
            wro[0 * NN + n] = wv0; wro[1 * NN + n] = wv1;
            wro[2 * NN + n] = wv2; wro[3 * NN + n] = wv3;
            float acc = wv0 + wv1 + wv2 + wv3;
            acc += fmaf(sa[0], wrp[0 * NN + n] - wl, wl);
            acc += fmaf(sa[1], wrp[1 * NN + n] - wl, wl);
            acc += fmaf(sa[2], wrp[2 * NN + n] - wl, wl);
            acc += fmaf(sa[3], wrp[3 * NN + n] - wl, wl);
            wuo[n] = GAMMA * wuprev[(size_t)b * NN + n] + acc;
        }
    }
    __syncthreads();   // phase-2 reads of s_e4 done; safe to reuse as lr

    // ---- final r_t merge across the 8 waves ----
    float4* lr = s_e4;
    if (row4 == 0) {
        #pragma unroll
        for (int r = 0; r < 4; r++) lr[wave * 64 + r * 16 + d4] = racc[r];
    }
    __syncthreads();
    if (t < 64) {
        const int r = t >> 4, dd = t & 15;
        float4 s = make_float4(0.f, 0.f, 0.f, 0.f);
        #pragma unroll
        for (int w = 0; w < 8; w++) {
            const float4 v = lr[w * 64 + r * 16 + dd];
            s.x += v.x; s.y += v.y; s.z += v.z; s.w += v.w;
        }
        const float inv = zi[r];
        const float4 rt = make_float4(s.x * inv, s.y * inv, s.z * inv, s.w * inv);
        *(float4*)(out + OUT_RT + (size_t)b * 256 + r * 64 + dd * 4) = rt;
        *(float4*)(out + (size_t)b * 768 + 512 + r * 64 + dd * 4) = rt;
    }
}

// ===================== host =====================
extern "C" void kernel_launch(void* const* d_in, const int* in_sizes, int n_in,
                              void* d_out, int out_size, void* d_ws, size_t ws_size,
                              hipStream_t stream)
{
    const float* x      = (const float*)d_in[0];
    const float* Mprev  = (const float*)d_in[1];
    const float* rprev  = (const float*)d_in[2];
    const float* hprev  = (const float*)d_in[3];
    const float* cprev  = (const float*)d_in[4];
    const float* wuprev = (const float*)d_in[5];
    const float* wrprev = (const float*)d_in[6];
    const float* Wih    = (const float*)d_in[7];
    const float* bih    = (const float*)d_in[8];
    const float* Whh    = (const float*)d_in[9];
    const float* bhh    = (const float*)d_in[10];
    const float* Wlin   = (const float*)d_in[11];
    const float* blin   = (const float*)d_in[12];
    float* out = (float*)d_out;

    unsigned* Abf  = (unsigned*)(out + OUT_WU);              // 2 MB   (dead until fused_mem)
    unsigned* Wlbf = Abf + (size_t)1048576;                  // +4 MB offset, 288 KB
    unsigned* Wbf  = (unsigned*)(out + OUT_WR);              // 4 MB   (dead until fused_mem)
    unsigned* Hbf  = (unsigned*)(out + OUT_RT);              // 1 MB   (dead until fused_mem)

    conv_all<<<1665, 256, 0, stream>>>(x, rprev, hprev, Wih, Whh, Wlin, Abf, Wbf, Wlbf);
    gemm_gates<<<dim3(32, 16), 256, 0, stream>>>(Abf, Wbf, bih, bhh, out);
    lstm_pw<<<512, 256, 0, stream>>>(cprev, out);
    gemm_p<<<dim3(9, 16), 256, 0, stream>>>(Hbf, Wlbf, blin, out);
    fused_mem<<<1024, 512, 0, stream>>>(Mprev, wrprev, wuprev, out);
}